// Round 1
// baseline (1312.789 us; speedup 1.0000x reference)
//
#include <hip/hip_runtime.h>
#include <hip/hip_bf16.h>

// Problem constants (fixed by the reference)
#define B_  256
#define T_  72
#define N_  5
#define F_  10
#define D_  128
#define HH_ 4
#define CC_ 32
#define FF_ 256
#define BT_ (B_*T_)   // 18432
#define E2MAX 32

// ---------------- ws layout (float offsets) ----------------
// [0..31]   anorm (25 used)
// [32..63]  src2 (int)
// [64..95]  dst2 (int)
// [96..103] csr_off (6 used, int)
// [104..135] csr_e (25 used, int)
// [256 ..]  z     : BT*128
// then      qkv   : BT*384
// then      obuf  : BT*128
#define WS_Z    256
#define WS_QKV  (WS_Z + BT_*D_)
#define WS_OBUF (WS_QKV + BT_*3*D_)

// ---------------------------------------------------------------------------
__global__ void setup_kernel(const int* __restrict__ ei, float* __restrict__ ws, int E) {
    if (threadIdx.x != 0 || blockIdx.x != 0) return;
    int* wsi = (int*)ws;
    const int N = N_;
    int E2 = E + N;
    int src2[E2MAX], dst2[E2MAX];
    for (int e = 0; e < E; ++e) { src2[e] = ei[e]; dst2[e] = ei[E + e]; }
    for (int n = 0; n < N; ++n) { src2[E + n] = n; dst2[E + n] = n; }
    float A[N_ * N_];
    for (int i = 0; i < N * N; ++i) A[i] = 0.f;
    for (int e = 0; e < E2; ++e) A[dst2[e] * N + src2[e]] += 1.f;
    float dinv[N_];
    for (int n = 0; n < N; ++n) {
        float s = 0.f;
        for (int j = 0; j < N; ++j) s += A[n * N + j];
        dinv[n] = (s > 0.f) ? rsqrtf(s) : 0.f;
    }
    for (int n = 0; n < N; ++n)
        for (int j = 0; j < N; ++j)
            ws[n * N + j] = dinv[n] * A[n * N + j] * dinv[j];
    // CSR by dst
    int cnt[N_];
    for (int n = 0; n < N; ++n) cnt[n] = 0;
    for (int e = 0; e < E2; ++e) cnt[dst2[e]]++;
    int off = 0;
    for (int n = 0; n < N; ++n) { wsi[96 + n] = off; off += cnt[n]; }
    wsi[96 + N] = off;
    int cur[N_];
    for (int n = 0; n < N; ++n) cur[n] = wsi[96 + n];
    for (int e = 0; e < E2; ++e) wsi[104 + cur[dst2[e]]++] = e;
    for (int e = 0; e < E2; ++e) { wsi[32 + e] = src2[e]; wsi[64 + e] = dst2[e]; }
}

// ---------------------------------------------------------------------------
// Fused: GCN -> tanh -> GAT (h, scores, segment softmax, agg) -> +bias -> LN
//        -> mean over nodes -> +positional encoding -> z
// one block per token (b,t), 128 threads
__global__ __launch_bounds__(128) void graph_kernel(
    const float* __restrict__ x, const float* __restrict__ gcn_w, const float* __restrict__ gcn_b,
    const float* __restrict__ gat_w, const float* __restrict__ a_src, const float* __restrict__ a_dst,
    const float* __restrict__ gat_b, const float* __restrict__ gln_g, const float* __restrict__ gln_b,
    const float* __restrict__ ws, float* __restrict__ z, int E2)
{
    const int tid = threadIdx.x;
    const int tok = blockIdx.x;
    const int t = tok % T_;

    __shared__ float s_x[N_][F_];
    __shared__ float s_xw[N_][64];
    __shared__ float s_gcn[N_][64];
    __shared__ float s_h[N_][D_];
    __shared__ float s_as[N_][HH_], s_ad[N_][HH_];
    __shared__ float s_alpha[E2MAX][HH_];
    __shared__ float s_anorm[N_ * N_];
    __shared__ int   s_src[E2MAX], s_csr_off[N_ + 1], s_csr_e[E2MAX];
    __shared__ float s_red[4];

    const int* wsi = (const int*)ws;
    if (tid < N_ * N_) s_anorm[tid] = ws[tid];
    if (tid < E2) { s_src[tid] = wsi[32 + tid]; s_csr_e[tid] = wsi[104 + tid]; }
    if (tid < N_ + 1) s_csr_off[tid] = wsi[96 + tid];
    if (tid < N_ * F_) s_x[tid / F_][tid % F_] = x[tok * (N_ * F_) + tid];
    __syncthreads();

    // xw = x @ gcn_w + gcn_b   (5 x 64)
    for (int idx = tid; idx < N_ * 64; idx += 128) {
        int n = idx >> 6, kk = idx & 63;
        float acc = gcn_b[kk];
        #pragma unroll
        for (int f = 0; f < F_; ++f) acc += s_x[n][f] * gcn_w[f * 64 + kk];
        s_xw[n][kk] = acc;
    }
    __syncthreads();
    // gcn = tanh(Anorm @ xw)
    for (int idx = tid; idx < N_ * 64; idx += 128) {
        int n = idx >> 6, kk = idx & 63;
        float s = 0.f;
        #pragma unroll
        for (int j = 0; j < N_; ++j) s += s_anorm[n * N_ + j] * s_xw[j][kk];
        s_gcn[n][kk] = tanhf(s);
    }
    __syncthreads();

    // h = gcn @ gat_w  (5 x 128), plus a_s/a_d reductions
    const int d = tid;
    float hh[N_] = {0.f, 0.f, 0.f, 0.f, 0.f};
    for (int k = 0; k < 64; ++k) {
        float w = gat_w[k * D_ + d];
        #pragma unroll
        for (int n = 0; n < N_; ++n) hh[n] += s_gcn[n][k] * w;
    }
    const float asd = a_src[d], add_ = a_dst[d];
    #pragma unroll
    for (int n = 0; n < N_; ++n) {
        s_h[n][d] = hh[n];
        float va = hh[n] * asd, vb = hh[n] * add_;
        #pragma unroll
        for (int m = 16; m >= 1; m >>= 1) { va += __shfl_xor(va, m); vb += __shfl_xor(vb, m); }
        if ((d & 31) == 0) { s_as[n][d >> 5] = va; s_ad[n][d >> 5] = vb; }
    }
    __syncthreads();

    // attention coefficients per (dst, head)
    if (tid < N_ * HH_) {
        int dn = tid >> 2, head = tid & 3;
        int j0 = s_csr_off[dn], j1 = s_csr_off[dn + 1];
        float mx = -1e30f;
        for (int j = j0; j < j1; ++j) {
            int e = s_csr_e[j];
            float ev = s_as[s_src[e]][head] + s_ad[dn][head];
            ev = ev > 0.f ? ev : 0.2f * ev;
            mx = fmaxf(mx, ev);
        }
        float den = 0.f;
        for (int j = j0; j < j1; ++j) {
            int e = s_csr_e[j];
            float ev = s_as[s_src[e]][head] + s_ad[dn][head];
            ev = ev > 0.f ? ev : 0.2f * ev;
            den += __expf(ev - mx);
        }
        float rden = 1.f / den;
        for (int j = j0; j < j1; ++j) {
            int e = s_csr_e[j];
            float ev = s_as[s_src[e]][head] + s_ad[dn][head];
            ev = ev > 0.f ? ev : 0.2f * ev;
            s_alpha[e][head] = __expf(ev - mx) * rden;
        }
    }
    __syncthreads();

    // aggregate + gat bias + LayerNorm + mean over nodes
    const int head = d >> 5;
    float zacc = 0.f;
    const float gb = gat_b[d], gg = gln_g[d], gbb = gln_b[d];
    for (int n = 0; n < N_; ++n) {
        float agg = 0.f;
        int j0 = s_csr_off[n], j1 = s_csr_off[n + 1];
        for (int j = j0; j < j1; ++j) {
            int e = s_csr_e[j];
            agg += s_alpha[e][head] * s_h[s_src[e]][d];
        }
        float val = agg + gb;
        float a = val, q = val * val;
        #pragma unroll
        for (int m = 32; m >= 1; m >>= 1) { a += __shfl_xor(a, m); q += __shfl_xor(q, m); }
        if ((tid & 63) == 0) { s_red[(tid >> 6) * 2] = a; s_red[(tid >> 6) * 2 + 1] = q; }
        __syncthreads();
        float sum = s_red[0] + s_red[2], sq = s_red[1] + s_red[3];
        __syncthreads();
        float mu = sum * (1.f / D_);
        float var = sq * (1.f / D_) - mu * mu;
        float rstd = rsqrtf(var + 1e-5f);
        zacc += (val - mu) * rstd * gg + gbb;
    }
    zacc *= (1.f / N_);

    // positional encoding
    const float cpe = -9.210340371976184f / (float)D_; // -ln(10000)/D
    float dv = __expf((float)(d & ~1) * cpe);
    float ang = (float)t * dv;
    float pe = (d & 1) ? __cosf(ang) : __sinf(ang);
    z[(size_t)tok * D_ + d] = zacc + pe;
}

// ---------------------------------------------------------------------------
// qkv = z @ Wqkv + b   : 16 tokens per block, 384 threads (one output col each)
__global__ __launch_bounds__(384) void qkv_kernel(
    const float* __restrict__ z, const float* __restrict__ W, const float* __restrict__ bias,
    float* __restrict__ qkv)
{
    __shared__ float s_z[16][D_];
    const int tid = threadIdx.x;
    const int tok0 = blockIdx.x * 16;
    for (int idx = tid; idx < 16 * D_; idx += 384) s_z[idx >> 7][idx & 127] = z[(size_t)tok0 * D_ + idx];
    __syncthreads();
    float acc[16];
    #pragma unroll
    for (int m = 0; m < 16; ++m) acc[m] = 0.f;
    for (int k = 0; k < D_; ++k) {
        float w = W[k * 384 + tid];
        #pragma unroll
        for (int m = 0; m < 16; ++m) acc[m] += s_z[m][k] * w;
    }
    const float bb = bias[tid];
    #pragma unroll
    for (int m = 0; m < 16; ++m) qkv[(size_t)(tok0 + m) * 384 + tid] = acc[m] + bb;
}

// ---------------------------------------------------------------------------
// full attention for one (batch, head): scores + softmax + PV, all in LDS
__global__ __launch_bounds__(256) void attn_kernel(
    const float* __restrict__ qkv, float* __restrict__ obuf)
{
    const int bh = blockIdx.x;
    const int b = bh >> 2, h = bh & 3;
    __shared__ float s_q[T_][33], s_k[T_][33], s_v[T_][33];
    __shared__ float s_p[T_][73];
    const int tid = threadIdx.x;
    const float* base = qkv + (size_t)b * T_ * 384 + h * 32;
    for (int idx = tid; idx < T_ * 32; idx += 256) {
        int i = idx >> 5, c = idx & 31;
        s_q[i][c] = base[i * 384 + c];
        s_k[i][c] = base[i * 384 + 128 + c];
        s_v[i][c] = base[i * 384 + 256 + c];
    }
    __syncthreads();
    const float scale = 0.17677669529663687f; // 1/sqrt(32)
    for (int idx = tid; idx < T_ * T_; idx += 256) {
        int i = idx / T_, j = idx - i * T_;
        float s = 0.f;
        #pragma unroll
        for (int c = 0; c < 32; ++c) s += s_q[i][c] * s_k[j][c];
        s_p[i][j] = s * scale;
    }
    __syncthreads();
    if (tid < T_) {
        float mx = -1e30f;
        for (int j = 0; j < T_; ++j) mx = fmaxf(mx, s_p[tid][j]);
        float den = 0.f;
        for (int j = 0; j < T_; ++j) { float e = __expf(s_p[tid][j] - mx); s_p[tid][j] = e; den += e; }
        float r = 1.f / den;
        for (int j = 0; j < T_; ++j) s_p[tid][j] *= r;
    }
    __syncthreads();
    for (int idx = tid; idx < T_ * 32; idx += 256) {
        int i = idx >> 5, c = idx & 31;
        float o = 0.f;
        for (int j = 0; j < T_; ++j) o += s_p[i][j] * s_v[j][c];
        obuf[(size_t)(b * T_ + i) * D_ + h * 32 + c] = o;
    }
}

// ---------------------------------------------------------------------------
// z = LN(z + obuf @ Wo + bo) : 16 tokens per block, 128 threads
__global__ __launch_bounds__(128) void oproj_kernel(
    const float* __restrict__ obuf, const float* __restrict__ W, const float* __restrict__ bias,
    const float* __restrict__ g, const float* __restrict__ be, float* __restrict__ z)
{
    __shared__ float s_o[16][D_];
    __shared__ float s_red[4];
    const int tid = threadIdx.x;
    const int tok0 = blockIdx.x * 16;
    for (int idx = tid; idx < 16 * D_; idx += 128) s_o[idx >> 7][idx & 127] = obuf[(size_t)tok0 * D_ + idx];
    __syncthreads();
    float acc[16];
    #pragma unroll
    for (int m = 0; m < 16; ++m) acc[m] = 0.f;
    for (int k = 0; k < D_; ++k) {
        float w = W[k * D_ + tid];
        #pragma unroll
        for (int m = 0; m < 16; ++m) acc[m] += s_o[m][k] * w;
    }
    const float bb = bias[tid], gg = g[tid], bee = be[tid];
    for (int m = 0; m < 16; ++m) {
        float val = z[(size_t)(tok0 + m) * D_ + tid] + acc[m] + bb;
        float a = val, q = val * val;
        #pragma unroll
        for (int mm = 32; mm >= 1; mm >>= 1) { a += __shfl_xor(a, mm); q += __shfl_xor(q, mm); }
        if ((tid & 63) == 0) { s_red[(tid >> 6) * 2] = a; s_red[(tid >> 6) * 2 + 1] = q; }
        __syncthreads();
        float sum = s_red[0] + s_red[2], sq = s_red[1] + s_red[3];
        __syncthreads();
        float mu = sum * (1.f / D_), var = sq * (1.f / D_) - mu * mu;
        float rstd = rsqrtf(var + 1e-5f);
        z[(size_t)(tok0 + m) * D_ + tid] = (val - mu) * rstd * gg + bee;
    }
}

// ---------------------------------------------------------------------------
// z = LN(z + relu(z@W1+b1)@W2 + b2) : 16 tokens per block, 128 threads
__global__ __launch_bounds__(128) void ff_kernel(
    const float* __restrict__ W1, const float* __restrict__ b1,
    const float* __restrict__ W2, const float* __restrict__ b2,
    const float* __restrict__ g, const float* __restrict__ be, float* __restrict__ z)
{
    __shared__ float s_z[16][D_];
    __shared__ float s_f[16][FF_];
    __shared__ float s_red[4];
    const int tid = threadIdx.x;
    const int tok0 = blockIdx.x * 16;
    for (int idx = tid; idx < 16 * D_; idx += 128) s_z[idx >> 7][idx & 127] = z[(size_t)tok0 * D_ + idx];
    __syncthreads();
    #pragma unroll
    for (int half = 0; half < 2; ++half) {
        const int j = half * 128 + tid;
        float acc[16];
        #pragma unroll
        for (int m = 0; m < 16; ++m) acc[m] = 0.f;
        for (int k = 0; k < D_; ++k) {
            float w = W1[k * FF_ + j];
            #pragma unroll
            for (int m = 0; m < 16; ++m) acc[m] += s_z[m][k] * w;
        }
        const float bb = b1[j];
        #pragma unroll
        for (int m = 0; m < 16; ++m) s_f[m][j] = fmaxf(acc[m] + bb, 0.f);
    }
    __syncthreads();
    float acc2[16];
    #pragma unroll
    for (int m = 0; m < 16; ++m) acc2[m] = 0.f;
    for (int kk = 0; kk < FF_; ++kk) {
        float w = W2[kk * D_ + tid];
        #pragma unroll
        for (int m = 0; m < 16; ++m) acc2[m] += s_f[m][kk] * w;
    }
    const float bb = b2[tid], gg = g[tid], bee = be[tid];
    for (int m = 0; m < 16; ++m) {
        float val = s_z[m][tid] + acc2[m] + bb;
        float a = val, q = val * val;
        #pragma unroll
        for (int mm = 32; mm >= 1; mm >>= 1) { a += __shfl_xor(a, mm); q += __shfl_xor(q, mm); }
        if ((tid & 63) == 0) { s_red[(tid >> 6) * 2] = a; s_red[(tid >> 6) * 2 + 1] = q; }
        __syncthreads();
        float sum = s_red[0] + s_red[2], sq = s_red[1] + s_red[3];
        __syncthreads();
        float mu = sum * (1.f / D_), var = sq * (1.f / D_) - mu * mu;
        float rstd = rsqrtf(var + 1e-5f);
        z[(size_t)(tok0 + m) * D_ + tid] = (val - mu) * rstd * gg + bee;
    }
}

// ---------------------------------------------------------------------------
// heads: last = z[:, -1]; out[k,b,:] = relu(last@hw1[k]+hb1[k]) @ hw2[k] + hb2[k]
__global__ __launch_bounds__(64) void heads_kernel(
    const float* __restrict__ z, const float* __restrict__ hw1, const float* __restrict__ hb1,
    const float* __restrict__ hw2, const float* __restrict__ hb2, float* __restrict__ out)
{
    const int k = blockIdx.x >> 8;          // 0..5
    const int b = blockIdx.x & 255;         // 0..255
    const int tid = threadIdx.x;
    __shared__ float s_last[D_];
    __shared__ float s_h1[64];
    const float* zr = z + (size_t)(b * T_ + (T_ - 1)) * D_;
    s_last[tid] = zr[tid];
    s_last[tid + 64] = zr[tid + 64];
    __syncthreads();
    float acc = hb1[k * 64 + tid];
    const float* w1 = hw1 + (size_t)k * D_ * 64;
    for (int dd = 0; dd < D_; ++dd) acc += s_last[dd] * w1[dd * 64 + tid];
    s_h1[tid] = fmaxf(acc, 0.f);
    __syncthreads();
    if (tid < 5) {
        float o = hb2[k * 5 + tid];
        const float* w2 = hw2 + (size_t)k * 64 * 5;
        for (int j = 0; j < 64; ++j) o += s_h1[j] * w2[j * 5 + tid];
        out[(size_t)k * (B_ * 5) + b * 5 + tid] = o;
    }
}

// ---------------------------------------------------------------------------
extern "C" void kernel_launch(void* const* d_in, const int* in_sizes, int n_in,
                              void* d_out, int out_size, void* d_ws, size_t ws_size,
                              hipStream_t stream) {
    const float* x      = (const float*)d_in[0];
    const int*   ei     = (const int*)  d_in[1];
    const float* gcn_w  = (const float*)d_in[2];
    const float* gcn_b  = (const float*)d_in[3];
    const float* gat_w  = (const float*)d_in[4];
    const float* a_src  = (const float*)d_in[5];
    const float* a_dst  = (const float*)d_in[6];
    const float* gat_b  = (const float*)d_in[7];
    const float* gln_g  = (const float*)d_in[8];
    const float* gln_b  = (const float*)d_in[9];
    const float* tw_qkv = (const float*)d_in[10];
    const float* tb_qkv = (const float*)d_in[11];
    const float* tw_o   = (const float*)d_in[12];
    const float* tb_o   = (const float*)d_in[13];
    const float* ln1_g  = (const float*)d_in[14];
    const float* ln1_b  = (const float*)d_in[15];
    const float* w_ff1  = (const float*)d_in[16];
    const float* b_ff1  = (const float*)d_in[17];
    const float* w_ff2  = (const float*)d_in[18];
    const float* b_ff2  = (const float*)d_in[19];
    const float* ln2_g  = (const float*)d_in[20];
    const float* ln2_b  = (const float*)d_in[21];
    const float* hw1    = (const float*)d_in[22];
    const float* hb1    = (const float*)d_in[23];
    const float* hw2    = (const float*)d_in[24];
    const float* hb2    = (const float*)d_in[25];
    float* out = (float*)d_out;
    float* ws  = (float*)d_ws;

    float* z    = ws + WS_Z;
    float* qkv  = ws + WS_QKV;
    float* obuf = ws + WS_OBUF;

    const int E = in_sizes[1] / 2;   // 20
    const int E2 = E + N_;           // 25

    setup_kernel<<<1, 64, 0, stream>>>(ei, ws, E);
    graph_kernel<<<BT_, 128, 0, stream>>>(x, gcn_w, gcn_b, gat_w, a_src, a_dst,
                                          gat_b, gln_g, gln_b, ws, z, E2);
    for (int i = 0; i < 3; ++i) {
        qkv_kernel<<<BT_ / 16, 384, 0, stream>>>(z, tw_qkv + (size_t)i * D_ * 3 * D_,
                                                 tb_qkv + (size_t)i * 3 * D_, qkv);
        attn_kernel<<<B_ * HH_, 256, 0, stream>>>(qkv, obuf);
        oproj_kernel<<<BT_ / 16, 128, 0, stream>>>(obuf, tw_o + (size_t)i * D_ * D_,
                                                   tb_o + (size_t)i * D_,
                                                   ln1_g + (size_t)i * D_, ln1_b + (size_t)i * D_, z);
        ff_kernel<<<BT_ / 16, 128, 0, stream>>>(w_ff1 + (size_t)i * D_ * FF_, b_ff1 + (size_t)i * FF_,
                                                w_ff2 + (size_t)i * FF_ * D_, b_ff2 + (size_t)i * D_,
                                                ln2_g + (size_t)i * D_, ln2_b + (size_t)i * D_, z);
    }
    heads_kernel<<<6 * B_, 64, 0, stream>>>(z, hw1, hb1, hw2, hb2, out);
}

// Round 2
// 886.940 us; speedup vs baseline: 1.4801x; 1.4801x over previous
//
#include <hip/hip_runtime.h>
#include <hip/hip_bf16.h>

// Problem constants (fixed by the reference)
#define B_  256
#define T_  72
#define N_  5
#define F_  10
#define D_  128
#define HH_ 4
#define CC_ 32
#define FF_ 256
#define BT_ (B_*T_)   // 18432
#define E2MAX 32

// ---------------- ws layout (float offsets) ----------------
// [0..31]   anorm (25 used)
// [32..63]  src2 (int)
// [64..95]  dst2 (int)
// [96..103] csr_off (6 used, int)
// [104..135] csr_e (25 used, int)
// [256 ..]  z     : BT*128
// then      qkv   : BT*384   (gcn buffer BT*320 aliases here before layer 0)
// then      obuf  : BT*128
#define WS_Z    256
#define WS_QKV  (WS_Z + BT_*D_)
#define WS_OBUF (WS_QKV + BT_*3*D_)

// ---------------------------------------------------------------------------
__global__ void setup_kernel(const int* __restrict__ ei, float* __restrict__ ws, int E) {
    if (threadIdx.x != 0 || blockIdx.x != 0) return;
    int* wsi = (int*)ws;
    const int N = N_;
    int E2 = E + N;
    int src2[E2MAX], dst2[E2MAX];
    for (int e = 0; e < E; ++e) { src2[e] = ei[e]; dst2[e] = ei[E + e]; }
    for (int n = 0; n < N; ++n) { src2[E + n] = n; dst2[E + n] = n; }
    float A[N_ * N_];
    for (int i = 0; i < N * N; ++i) A[i] = 0.f;
    for (int e = 0; e < E2; ++e) A[dst2[e] * N + src2[e]] += 1.f;
    float dinv[N_];
    for (int n = 0; n < N; ++n) {
        float s = 0.f;
        for (int j = 0; j < N; ++j) s += A[n * N + j];
        dinv[n] = (s > 0.f) ? rsqrtf(s) : 0.f;
    }
    for (int n = 0; n < N; ++n)
        for (int j = 0; j < N; ++j)
            ws[n * N + j] = dinv[n] * A[n * N + j] * dinv[j];
    // CSR by dst
    int cnt[N_];
    for (int n = 0; n < N; ++n) cnt[n] = 0;
    for (int e = 0; e < E2; ++e) cnt[dst2[e]]++;
    int off = 0;
    for (int n = 0; n < N; ++n) { wsi[96 + n] = off; off += cnt[n]; }
    wsi[96 + N] = off;
    int cur[N_];
    for (int n = 0; n < N; ++n) cur[n] = wsi[96 + n];
    for (int e = 0; e < E2; ++e) wsi[104 + cur[dst2[e]]++] = e;
    for (int e = 0; e < E2; ++e) { wsi[32 + e] = src2[e]; wsi[64 + e] = dst2[e]; }
}

// ---------------------------------------------------------------------------
// gcn = tanh(Anorm @ (x @ gcn_w + b)) -> gcn buffer [token][n*64+k]
// 4 tokens per 256-thread block; thread = (token_local, k)
__global__ __launch_bounds__(256) void gcn_kernel(
    const float* __restrict__ x, const float* __restrict__ gcn_w, const float* __restrict__ gcn_b,
    const float* __restrict__ ws, float* __restrict__ gcn)
{
    const int tid = threadIdx.x;
    const int tl = tid >> 6, k = tid & 63;
    const int tok = blockIdx.x * 4 + tl;
    __shared__ float s_x[4][N_ * F_];
    __shared__ float s_an[N_ * N_];
    if (tid < 4 * N_ * F_) ((float*)s_x)[tid] = x[(size_t)blockIdx.x * (4 * N_ * F_) + tid];
    if (tid < N_ * N_) s_an[tid] = ws[tid];
    __syncthreads();
    float w[F_];
    #pragma unroll
    for (int f = 0; f < F_; ++f) w[f] = gcn_w[f * 64 + k];
    const float bk = gcn_b[k];
    float xw[N_];
    #pragma unroll
    for (int n = 0; n < N_; ++n) {
        float acc = bk;
        #pragma unroll
        for (int f = 0; f < F_; ++f) acc += s_x[tl][n * F_ + f] * w[f];
        xw[n] = acc;
    }
    float* gout = gcn + (size_t)tok * (N_ * 64);
    #pragma unroll
    for (int n = 0; n < N_; ++n) {
        float s = 0.f;
        #pragma unroll
        for (int j = 0; j < N_; ++j) s += s_an[n * N_ + j] * xw[j];
        // fast tanh: sign-safe, no NaN at large |s|
        float ax = fabsf(s);
        float e = __expf(2.f * ax);
        float t = 1.f - 2.f / (e + 1.f);
        gout[n * 64 + k] = copysignf(t, s);
    }
}

// ---------------------------------------------------------------------------
// GAT (h, scores, segment softmax, agg) -> +bias -> LN -> mean over nodes -> +PE
// 2 tokens per 256-thread block (128 threads per token, one per feature dim d)
__global__ __launch_bounds__(256, 4) void gat_kernel(
    const float* __restrict__ gcn, const float* __restrict__ gat_w,
    const float* __restrict__ a_src, const float* __restrict__ a_dst,
    const float* __restrict__ gat_b, const float* __restrict__ gln_g, const float* __restrict__ gln_b,
    const float* __restrict__ ws, float* __restrict__ z, int E2)
{
    const int tid = threadIdx.x;
    const int tl  = tid >> 7;        // token slot within block
    const int d   = tid & 127;       // feature dim
    const int wv  = (tid >> 6) & 1;  // wave within the 128-thread group
    const int tok = blockIdx.x * 2 + tl;
    const int t   = tok % T_;

    __shared__ float s_gcn[2][N_][64];
    __shared__ float s_h[2][N_][D_];
    __shared__ float s_as[2][N_][HH_], s_ad[2][N_][HH_];
    __shared__ float s_alpha[2][E2MAX][HH_];
    __shared__ int   s_src[E2MAX], s_csr_off[N_ + 1], s_csr_e[E2MAX];
    __shared__ float s_red[2][N_][2][2];

    const int* wsi = (const int*)ws;
    if (tid < E2) { s_src[tid] = wsi[32 + tid]; s_csr_e[tid] = wsi[104 + tid]; }
    if (tid < N_ + 1) s_csr_off[tid] = wsi[96 + tid];
    {
        const float* g0 = gcn + (size_t)tok * (N_ * 64);
        for (int i = d; i < N_ * 64; i += 128) ((float*)s_gcn[tl])[i] = g0[i];
    }
    __syncthreads();

    // h[n][d] = sum_k gcn[n][k] * gat_w[k][d]
    float hh[N_] = {0.f, 0.f, 0.f, 0.f, 0.f};
    for (int k4 = 0; k4 < 64; k4 += 4) {
        float4 g[N_];
        #pragma unroll
        for (int n = 0; n < N_; ++n) g[n] = *(const float4*)&s_gcn[tl][n][k4];
        #pragma unroll
        for (int kk = 0; kk < 4; ++kk) {
            float wval = gat_w[(k4 + kk) * D_ + d];
            #pragma unroll
            for (int n = 0; n < N_; ++n) hh[n] += ((const float*)&g[n])[kk] * wval;
        }
    }
    #pragma unroll
    for (int n = 0; n < N_; ++n) s_h[tl][n][d] = hh[n];

    // a_s / a_d: reduce over the 32 lanes of each head (10 interleaved chains)
    const float asd = a_src[d], add_ = a_dst[d];
    float va[N_], vb[N_];
    #pragma unroll
    for (int n = 0; n < N_; ++n) { va[n] = hh[n] * asd; vb[n] = hh[n] * add_; }
    #pragma unroll
    for (int m = 16; m >= 1; m >>= 1) {
        #pragma unroll
        for (int n = 0; n < N_; ++n) { va[n] += __shfl_xor(va[n], m); vb[n] += __shfl_xor(vb[n], m); }
    }
    if ((d & 31) == 0) {
        int head = d >> 5;
        #pragma unroll
        for (int n = 0; n < N_; ++n) { s_as[tl][n][head] = va[n]; s_ad[tl][n][head] = vb[n]; }
    }
    __syncthreads();

    // attention coefficients per (token_slot, dst, head) — 40 threads
    if (tid < 2 * N_ * HH_) {
        int tg = tid / (N_ * HH_), idx = tid % (N_ * HH_);
        int dn = idx >> 2, head = idx & 3;
        int j0 = s_csr_off[dn], j1 = s_csr_off[dn + 1];
        float adv = s_ad[tg][dn][head];
        float mx = -1e30f;
        for (int j = j0; j < j1; ++j) {
            int e = s_csr_e[j];
            float ev = s_as[tg][s_src[e]][head] + adv;
            ev = ev > 0.f ? ev : 0.2f * ev;
            mx = fmaxf(mx, ev);
        }
        float den = 0.f;
        for (int j = j0; j < j1; ++j) {
            int e = s_csr_e[j];
            float ev = s_as[tg][s_src[e]][head] + adv;
            ev = ev > 0.f ? ev : 0.2f * ev;
            float ex = __expf(ev - mx);
            den += ex;
            s_alpha[tg][e][head] = ex;
        }
        float r = 1.f / den;
        for (int j = j0; j < j1; ++j) s_alpha[tg][s_csr_e[j]][head] *= r;
    }
    __syncthreads();

    // aggregate + bias, then all 5 LayerNorms with one interleaved shuffle pass
    const int head = d >> 5;
    const float gb = gat_b[d];
    float val[N_];
    #pragma unroll
    for (int n = 0; n < N_; ++n) {
        float agg = 0.f;
        int j0 = s_csr_off[n], j1 = s_csr_off[n + 1];
        for (int j = j0; j < j1; ++j) {
            int e = s_csr_e[j];
            agg += s_alpha[tl][e][head] * s_h[tl][s_src[e]][d];
        }
        val[n] = agg + gb;
    }
    float sa[N_], sq[N_];
    #pragma unroll
    for (int n = 0; n < N_; ++n) { sa[n] = val[n]; sq[n] = val[n] * val[n]; }
    #pragma unroll
    for (int m = 32; m >= 1; m >>= 1) {
        #pragma unroll
        for (int n = 0; n < N_; ++n) { sa[n] += __shfl_xor(sa[n], m); sq[n] += __shfl_xor(sq[n], m); }
    }
    if ((tid & 63) == 0) {
        #pragma unroll
        for (int n = 0; n < N_; ++n) { s_red[tl][n][wv][0] = sa[n]; s_red[tl][n][wv][1] = sq[n]; }
    }
    __syncthreads();

    float zacc = 0.f;
    const float gg = gln_g[d], gbb = gln_b[d];
    #pragma unroll
    for (int n = 0; n < N_; ++n) {
        float sum = s_red[tl][n][0][0] + s_red[tl][n][1][0];
        float sqq = s_red[tl][n][0][1] + s_red[tl][n][1][1];
        float mu = sum * (1.f / D_);
        float var = sqq * (1.f / D_) - mu * mu;
        float rstd = rsqrtf(var + 1e-5f);
        zacc += (val[n] - mu) * rstd * gg + gbb;
    }
    zacc *= (1.f / N_);

    // positional encoding
    const float cpe = -9.210340371976184f / (float)D_; // -ln(10000)/D
    float dv = __expf((float)(d & ~1) * cpe);
    float ang = (float)t * dv;
    float pe = (d & 1) ? __cosf(ang) : __sinf(ang);
    z[(size_t)tok * D_ + d] = zacc + pe;
}

// ---------------------------------------------------------------------------
// qkv = z @ Wqkv + b   : 16 tokens per block, 384 threads (one output col each)
__global__ __launch_bounds__(384) void qkv_kernel(
    const float* __restrict__ z, const float* __restrict__ W, const float* __restrict__ bias,
    float* __restrict__ qkv)
{
    __shared__ float s_z[16][D_];
    const int tid = threadIdx.x;
    const int tok0 = blockIdx.x * 16;
    for (int idx = tid; idx < 16 * D_; idx += 384) s_z[idx >> 7][idx & 127] = z[(size_t)tok0 * D_ + idx];
    __syncthreads();
    float acc[16];
    #pragma unroll
    for (int m = 0; m < 16; ++m) acc[m] = 0.f;
    for (int k = 0; k < D_; ++k) {
        float w = W[k * 384 + tid];
        #pragma unroll
        for (int m = 0; m < 16; ++m) acc[m] += s_z[m][k] * w;
    }
    const float bb = bias[tid];
    #pragma unroll
    for (int m = 0; m < 16; ++m) qkv[(size_t)(tok0 + m) * 384 + tid] = acc[m] + bb;
}

// ---------------------------------------------------------------------------
// full attention for one (batch, head): scores + softmax + PV, all in LDS
__global__ __launch_bounds__(256) void attn_kernel(
    const float* __restrict__ qkv, float* __restrict__ obuf)
{
    const int bh = blockIdx.x;
    const int b = bh >> 2, h = bh & 3;
    __shared__ float s_q[T_][33], s_k[T_][33], s_v[T_][33];
    __shared__ float s_p[T_][73];
    const int tid = threadIdx.x;
    const float* base = qkv + (size_t)b * T_ * 384 + h * 32;
    for (int idx = tid; idx < T_ * 32; idx += 256) {
        int i = idx >> 5, c = idx & 31;
        s_q[i][c] = base[i * 384 + c];
        s_k[i][c] = base[i * 384 + 128 + c];
        s_v[i][c] = base[i * 384 + 256 + c];
    }
    __syncthreads();
    const float scale = 0.17677669529663687f; // 1/sqrt(32)
    for (int idx = tid; idx < T_ * T_; idx += 256) {
        int i = idx / T_, j = idx - i * T_;
        float s = 0.f;
        #pragma unroll
        for (int c = 0; c < 32; ++c) s += s_q[i][c] * s_k[j][c];
        s_p[i][j] = s * scale;
    }
    __syncthreads();
    if (tid < T_) {
        float mx = -1e30f;
        for (int j = 0; j < T_; ++j) mx = fmaxf(mx, s_p[tid][j]);
        float den = 0.f;
        for (int j = 0; j < T_; ++j) { float e = __expf(s_p[tid][j] - mx); s_p[tid][j] = e; den += e; }
        float r = 1.f / den;
        for (int j = 0; j < T_; ++j) s_p[tid][j] *= r;
    }
    __syncthreads();
    for (int idx = tid; idx < T_ * 32; idx += 256) {
        int i = idx >> 5, c = idx & 31;
        float o = 0.f;
        for (int j = 0; j < T_; ++j) o += s_p[i][j] * s_v[j][c];
        obuf[(size_t)(b * T_ + i) * D_ + h * 32 + c] = o;
    }
}

// ---------------------------------------------------------------------------
// z = LN(z + obuf @ Wo + bo) : 16 tokens per block, 128 threads
__global__ __launch_bounds__(128) void oproj_kernel(
    const float* __restrict__ obuf, const float* __restrict__ W, const float* __restrict__ bias,
    const float* __restrict__ g, const float* __restrict__ be, float* __restrict__ z)
{
    __shared__ float s_o[16][D_];
    __shared__ float s_red[4];
    const int tid = threadIdx.x;
    const int tok0 = blockIdx.x * 16;
    for (int idx = tid; idx < 16 * D_; idx += 128) s_o[idx >> 7][idx & 127] = obuf[(size_t)tok0 * D_ + idx];
    __syncthreads();
    float acc[16];
    #pragma unroll
    for (int m = 0; m < 16; ++m) acc[m] = 0.f;
    for (int k = 0; k < D_; ++k) {
        float w = W[k * D_ + tid];
        #pragma unroll
        for (int m = 0; m < 16; ++m) acc[m] += s_o[m][k] * w;
    }
    const float bb = bias[tid], gg = g[tid], bee = be[tid];
    for (int m = 0; m < 16; ++m) {
        float val = z[(size_t)(tok0 + m) * D_ + tid] + acc[m] + bb;
        float a = val, q = val * val;
        #pragma unroll
        for (int mm = 32; mm >= 1; mm >>= 1) { a += __shfl_xor(a, mm); q += __shfl_xor(q, mm); }
        if ((tid & 63) == 0) { s_red[(tid >> 6) * 2] = a; s_red[(tid >> 6) * 2 + 1] = q; }
        __syncthreads();
        float sum = s_red[0] + s_red[2], sq = s_red[1] + s_red[3];
        __syncthreads();
        float mu = sum * (1.f / D_), var = sq * (1.f / D_) - mu * mu;
        float rstd = rsqrtf(var + 1e-5f);
        z[(size_t)(tok0 + m) * D_ + tid] = (val - mu) * rstd * gg + bee;
    }
}

// ---------------------------------------------------------------------------
// z = LN(z + relu(z@W1+b1)@W2 + b2) : 16 tokens per block, 128 threads
__global__ __launch_bounds__(128) void ff_kernel(
    const float* __restrict__ W1, const float* __restrict__ b1,
    const float* __restrict__ W2, const float* __restrict__ b2,
    const float* __restrict__ g, const float* __restrict__ be, float* __restrict__ z)
{
    __shared__ float s_z[16][D_];
    __shared__ float s_f[16][FF_];
    __shared__ float s_red[4];
    const int tid = threadIdx.x;
    const int tok0 = blockIdx.x * 16;
    for (int idx = tid; idx < 16 * D_; idx += 128) s_z[idx >> 7][idx & 127] = z[(size_t)tok0 * D_ + idx];
    __syncthreads();
    #pragma unroll
    for (int half = 0; half < 2; ++half) {
        const int j = half * 128 + tid;
        float acc[16];
        #pragma unroll
        for (int m = 0; m < 16; ++m) acc[m] = 0.f;
        for (int k = 0; k < D_; ++k) {
            float w = W1[k * FF_ + j];
            #pragma unroll
            for (int m = 0; m < 16; ++m) acc[m] += s_z[m][k] * w;
        }
        const float bb = b1[j];
        #pragma unroll
        for (int m = 0; m < 16; ++m) s_f[m][j] = fmaxf(acc[m] + bb, 0.f);
    }
    __syncthreads();
    float acc2[16];
    #pragma unroll
    for (int m = 0; m < 16; ++m) acc2[m] = 0.f;
    for (int kk = 0; kk < FF_; ++kk) {
        float w = W2[kk * D_ + tid];
        #pragma unroll
        for (int m = 0; m < 16; ++m) acc2[m] += s_f[m][kk] * w;
    }
    const float bb = b2[tid], gg = g[tid], bee = be[tid];
    for (int m = 0; m < 16; ++m) {
        float val = s_z[m][tid] + acc2[m] + bb;
        float a = val, q = val * val;
        #pragma unroll
        for (int mm = 32; mm >= 1; mm >>= 1) { a += __shfl_xor(a, mm); q += __shfl_xor(q, mm); }
        if ((tid & 63) == 0) { s_red[(tid >> 6) * 2] = a; s_red[(tid >> 6) * 2 + 1] = q; }
        __syncthreads();
        float sum = s_red[0] + s_red[2], sq = s_red[1] + s_red[3];
        __syncthreads();
        float mu = sum * (1.f / D_), var = sq * (1.f / D_) - mu * mu;
        float rstd = rsqrtf(var + 1e-5f);
        z[(size_t)(tok0 + m) * D_ + tid] = (val - mu) * rstd * gg + bee;
    }
}

// ---------------------------------------------------------------------------
// heads: last = z[:, -1]; out[k,b,:] = relu(last@hw1[k]+hb1[k]) @ hw2[k] + hb2[k]
__global__ __launch_bounds__(64) void heads_kernel(
    const float* __restrict__ z, const float* __restrict__ hw1, const float* __restrict__ hb1,
    const float* __restrict__ hw2, const float* __restrict__ hb2, float* __restrict__ out)
{
    const int k = blockIdx.x >> 8;          // 0..5
    const int b = blockIdx.x & 255;         // 0..255
    const int tid = threadIdx.x;
    __shared__ float s_last[D_];
    __shared__ float s_h1[64];
    const float* zr = z + (size_t)(b * T_ + (T_ - 1)) * D_;
    s_last[tid] = zr[tid];
    s_last[tid + 64] = zr[tid + 64];
    __syncthreads();
    float acc = hb1[k * 64 + tid];
    const float* w1 = hw1 + (size_t)k * D_ * 64;
    for (int dd = 0; dd < D_; ++dd) acc += s_last[dd] * w1[dd * 64 + tid];
    s_h1[tid] = fmaxf(acc, 0.f);
    __syncthreads();
    if (tid < 5) {
        float o = hb2[k * 5 + tid];
        const float* w2 = hw2 + (size_t)k * 64 * 5;
        for (int j = 0; j < 64; ++j) o += s_h1[j] * w2[j * 5 + tid];
        out[(size_t)k * (B_ * 5) + b * 5 + tid] = o;
    }
}

// ---------------------------------------------------------------------------
extern "C" void kernel_launch(void* const* d_in, const int* in_sizes, int n_in,
                              void* d_out, int out_size, void* d_ws, size_t ws_size,
                              hipStream_t stream) {
    const float* x      = (const float*)d_in[0];
    const int*   ei     = (const int*)  d_in[1];
    const float* gcn_w  = (const float*)d_in[2];
    const float* gcn_b  = (const float*)d_in[3];
    const float* gat_w  = (const float*)d_in[4];
    const float* a_src  = (const float*)d_in[5];
    const float* a_dst  = (const float*)d_in[6];
    const float* gat_b  = (const float*)d_in[7];
    const float* gln_g  = (const float*)d_in[8];
    const float* gln_b  = (const float*)d_in[9];
    const float* tw_qkv = (const float*)d_in[10];
    const float* tb_qkv = (const float*)d_in[11];
    const float* tw_o   = (const float*)d_in[12];
    const float* tb_o   = (const float*)d_in[13];
    const float* ln1_g  = (const float*)d_in[14];
    const float* ln1_b  = (const float*)d_in[15];
    const float* w_ff1  = (const float*)d_in[16];
    const float* b_ff1  = (const float*)d_in[17];
    const float* w_ff2  = (const float*)d_in[18];
    const float* b_ff2  = (const float*)d_in[19];
    const float* ln2_g  = (const float*)d_in[20];
    const float* ln2_b  = (const float*)d_in[21];
    const float* hw1    = (const float*)d_in[22];
    const float* hb1    = (const float*)d_in[23];
    const float* hw2    = (const float*)d_in[24];
    const float* hb2    = (const float*)d_in[25];
    float* out = (float*)d_out;
    float* ws  = (float*)d_ws;

    float* z    = ws + WS_Z;
    float* qkv  = ws + WS_QKV;
    float* obuf = ws + WS_OBUF;
    float* gcn  = ws + WS_QKV;   // aliases qkv region (dead once layer 0 starts)

    const int E = in_sizes[1] / 2;   // 20
    const int E2 = E + N_;           // 25

    setup_kernel<<<1, 64, 0, stream>>>(ei, ws, E);
    gcn_kernel<<<BT_ / 4, 256, 0, stream>>>(x, gcn_w, gcn_b, ws, gcn);
    gat_kernel<<<BT_ / 2, 256, 0, stream>>>(gcn, gat_w, a_src, a_dst, gat_b,
                                            gln_g, gln_b, ws, z, E2);
    for (int i = 0; i < 3; ++i) {
        qkv_kernel<<<BT_ / 16, 384, 0, stream>>>(z, tw_qkv + (size_t)i * D_ * 3 * D_,
                                                 tb_qkv + (size_t)i * 3 * D_, qkv);
        attn_kernel<<<B_ * HH_, 256, 0, stream>>>(qkv, obuf);
        oproj_kernel<<<BT_ / 16, 128, 0, stream>>>(obuf, tw_o + (size_t)i * D_ * D_,
                                                   tb_o + (size_t)i * D_,
                                                   ln1_g + (size_t)i * D_, ln1_b + (size_t)i * D_, z);
        ff_kernel<<<BT_ / 16, 128, 0, stream>>>(w_ff1 + (size_t)i * D_ * FF_, b_ff1 + (size_t)i * FF_,
                                                w_ff2 + (size_t)i * FF_ * D_, b_ff2 + (size_t)i * D_,
                                                ln2_g + (size_t)i * D_, ln2_b + (size_t)i * D_, z);
    }
    heads_kernel<<<6 * B_, 64, 0, stream>>>(z, hw1, hb1, hw2, hb2, out);
}

// Round 3
// 505.887 us; speedup vs baseline: 2.5950x; 1.7532x over previous
//
#include <hip/hip_runtime.h>
#include <hip/hip_bf16.h>

// Problem constants (fixed by the reference)
#define B_  256
#define T_  72
#define N_  5
#define F_  10
#define D_  128
#define HH_ 4
#define CC_ 32
#define FF_ 256
#define BT_ (B_*T_)   // 18432
#define E2MAX 32

// ---------------- ws layout (float offsets) ----------------
#define WS_Z    256
#define WS_QKV  (WS_Z + BT_*D_)
#define WS_OBUF (WS_QKV + BT_*3*D_)
#define WS_WBF  (WS_OBUF + BT_*D_)      // bf16 weight region (196608 floats = 393216 bf16)

// bf16 weight offsets (in shorts, from WS_WBF base)
#define WOFF_QKV(i)  ((i)*49152)                 // [384][128]
#define WOFF_O(i)    (147456 + (i)*16384)        // [128][128]
#define WOFF_FF1(i)  (196608 + (i)*32768)        // [256][128]
#define WOFF_FF2(i)  (294912 + (i)*32768)        // [128][256]

typedef __attribute__((ext_vector_type(8))) short bf16x8;
typedef __attribute__((ext_vector_type(4))) float f32x4;

__device__ __forceinline__ unsigned short bf16_rne(float x) {
    unsigned u = __float_as_uint(x);
    unsigned r = (u + 0x7FFFu + ((u >> 16) & 1u)) >> 16;
    return (unsigned short)r;
}
__device__ __forceinline__ unsigned bf16pk(float a, float b) {
    return (unsigned)bf16_rne(a) | ((unsigned)bf16_rne(b) << 16);
}

// ---------------------------------------------------------------------------
__global__ void setup_kernel(const int* __restrict__ ei, float* __restrict__ ws, int E) {
    if (threadIdx.x != 0 || blockIdx.x != 0) return;
    int* wsi = (int*)ws;
    const int N = N_;
    int E2 = E + N;
    int src2[E2MAX], dst2[E2MAX];
    for (int e = 0; e < E; ++e) { src2[e] = ei[e]; dst2[e] = ei[E + e]; }
    for (int n = 0; n < N; ++n) { src2[E + n] = n; dst2[E + n] = n; }
    float A[N_ * N_];
    for (int i = 0; i < N * N; ++i) A[i] = 0.f;
    for (int e = 0; e < E2; ++e) A[dst2[e] * N + src2[e]] += 1.f;
    float dinv[N_];
    for (int n = 0; n < N; ++n) {
        float s = 0.f;
        for (int j = 0; j < N; ++j) s += A[n * N + j];
        dinv[n] = (s > 0.f) ? rsqrtf(s) : 0.f;
    }
    for (int n = 0; n < N; ++n)
        for (int j = 0; j < N; ++j)
            ws[n * N + j] = dinv[n] * A[n * N + j] * dinv[j];
    int cnt[N_];
    for (int n = 0; n < N; ++n) cnt[n] = 0;
    for (int e = 0; e < E2; ++e) cnt[dst2[e]]++;
    int off = 0;
    for (int n = 0; n < N; ++n) { wsi[96 + n] = off; off += cnt[n]; }
    wsi[96 + N] = off;
    int cur[N_];
    for (int n = 0; n < N; ++n) cur[n] = wsi[96 + n];
    for (int e = 0; e < E2; ++e) wsi[104 + cur[dst2[e]]++] = e;
    for (int e = 0; e < E2; ++e) { wsi[32 + e] = src2[e]; wsi[64 + e] = dst2[e]; }
}

// ---------------------------------------------------------------------------
// Weight prep: transpose R x C fp32 -> [C][R] bf16 into ws. 96 tiles of 64x64.
__global__ __launch_bounds__(256) void prep_kernel(
    const float* __restrict__ tw_qkv, const float* __restrict__ tw_o,
    const float* __restrict__ w_ff1, const float* __restrict__ w_ff2,
    short* __restrict__ wbf)
{
    __shared__ float s_t[64][65];
    const int tid = threadIdx.x;
    int t = blockIdx.x;
    int layer = t / 32, r32 = t % 32;
    const float* src; short* dst; int R, C, tr, tc;
    if (r32 < 12)      { src = tw_qkv + layer * (128*384); dst = wbf + WOFF_QKV(layer); R = 128; C = 384; tr = r32 / 6;  tc = r32 % 6; }
    else if (r32 < 16) { int q = r32 - 12; src = tw_o + layer * 16384; dst = wbf + WOFF_O(layer);  R = 128; C = 128; tr = q >> 1; tc = q & 1; }
    else if (r32 < 24) { int q = r32 - 16; src = w_ff1 + layer * 32768; dst = wbf + WOFF_FF1(layer); R = 128; C = 256; tr = q >> 2; tc = q & 3; }
    else               { int q = r32 - 24; src = w_ff2 + layer * 32768; dst = wbf + WOFF_FF2(layer); R = 256; C = 128; tr = q >> 1; tc = q & 1; }
    #pragma unroll
    for (int it = 0; it < 16; ++it) {
        int e = it * 256 + tid;
        int r = e >> 6, c = e & 63;
        s_t[r][c] = src[(size_t)(tr*64 + r) * C + tc*64 + c];
    }
    __syncthreads();
    #pragma unroll
    for (int it = 0; it < 16; ++it) {
        int e = it * 256 + tid;
        int c = e >> 6, r = e & 63;
        dst[(size_t)(tc*64 + c) * R + tr*64 + r] = (short)bf16_rne(s_t[r][c]);
    }
}

// ---------------------------------------------------------------------------
// MFMA helpers: A stored [rows][K] bf16 LDS, swizzle kelem ^ ((row&7)<<3).
__device__ __forceinline__ bf16x8 ld_frag(const short* s, int row, int kbase, int ldk) {
    return *(const bf16x8*)&s[row * ldk + (kbase ^ ((row & 7) << 3))];
}
// stage 64x128 fp32 -> bf16 swizzled LDS
__device__ __forceinline__ void stage_a(short* s_a, const float* __restrict__ src, int tid) {
    const float2* s2 = (const float2*)src;
    #pragma unroll
    for (int it = 0; it < 16; ++it) {
        int i2 = it * 256 + tid;
        int row = i2 >> 6, ke = (i2 & 63) * 2;
        float2 v = s2[i2];
        *(unsigned*)&s_a[row * 128 + (ke ^ ((row & 7) << 3))] = bf16pk(v.x, v.y);
    }
}
// stage 128 rows x 128 k of contiguous bf16 [N][128] -> swizzled LDS
__device__ __forceinline__ void stage_b(short* s_b, const short* __restrict__ src, int tid) {
    const uint4* s4 = (const uint4*)src;
    #pragma unroll
    for (int it = 0; it < 8; ++it) {
        int c = it * 256 + tid;
        int row = c >> 4, ke = (c & 15) * 8;
        *(uint4*)&s_b[row * 128 + (ke ^ ((row & 7) << 3))] = s4[c];
    }
}

// ---------------------------------------------------------------------------
// qkv = z @ Wqkv + b : M-tile 64, 4 waves, 3 N-chunks of 128
__global__ __launch_bounds__(256) void qkv_mfma(
    const float* __restrict__ z, const short* __restrict__ WT, const float* __restrict__ bias,
    float* __restrict__ qkv)
{
    __shared__ short s_a[64 * 128];
    __shared__ short s_b[128 * 128];
    const int tid = threadIdx.x;
    const int w = tid >> 6, lane = tid & 63;
    const int tok0 = blockIdx.x * 64;
    stage_a(s_a, z + (size_t)tok0 * 128, tid);
    __syncthreads();
    bf16x8 af[4];
    const int arow = w * 16 + (lane & 15);
    const int kf = (lane >> 4) * 8;
    #pragma unroll
    for (int k0 = 0; k0 < 4; ++k0) af[k0] = ld_frag(s_a, arow, k0 * 32 + kf, 128);

    for (int ch = 0; ch < 3; ++ch) {
        __syncthreads();
        stage_b(s_b, WT + ch * 128 * 128, tid);
        __syncthreads();
        #pragma unroll
        for (int n0 = 0; n0 < 8; ++n0) {
            const int ncol = ch * 128 + n0 * 16 + (lane & 15);
            const int brow = n0 * 16 + (lane & 15);
            float bv = bias[ncol];
            f32x4 acc = {bv, bv, bv, bv};
            #pragma unroll
            for (int k0 = 0; k0 < 4; ++k0) {
                bf16x8 bfg = ld_frag(s_b, brow, k0 * 32 + kf, 128);
                acc = __builtin_amdgcn_mfma_f32_16x16x32_bf16(af[k0], bfg, acc, 0, 0, 0);
            }
            const int r0 = tok0 + w * 16 + (lane >> 4) * 4;
            #pragma unroll
            for (int i = 0; i < 4; ++i)
                qkv[(size_t)(r0 + i) * 384 + ncol] = acc[i];
        }
    }
}

// ---------------------------------------------------------------------------
// z = LN(z + obuf @ Wo + bo) : MFMA + in-register LN (16-lane groups)
__global__ __launch_bounds__(256) void oproj_mfma(
    const float* __restrict__ obuf, const short* __restrict__ WT, const float* __restrict__ bias,
    const float* __restrict__ g, const float* __restrict__ be, float* __restrict__ z)
{
    __shared__ short s_a[64 * 128];
    __shared__ short s_b[128 * 128];
    const int tid = threadIdx.x;
    const int w = tid >> 6, lane = tid & 63;
    const int tok0 = blockIdx.x * 64;
    stage_a(s_a, obuf + (size_t)tok0 * 128, tid);
    stage_b(s_b, WT, tid);
    __syncthreads();
    bf16x8 af[4];
    const int arow = w * 16 + (lane & 15);
    const int kf = (lane >> 4) * 8;
    #pragma unroll
    for (int k0 = 0; k0 < 4; ++k0) af[k0] = ld_frag(s_a, arow, k0 * 32 + kf, 128);

    f32x4 acc[8];
    #pragma unroll
    for (int n0 = 0; n0 < 8; ++n0) {
        float bv = bias[n0 * 16 + (lane & 15)];
        acc[n0] = (f32x4){bv, bv, bv, bv};
        const int brow = n0 * 16 + (lane & 15);
        #pragma unroll
        for (int k0 = 0; k0 < 4; ++k0) {
            bf16x8 bfg = ld_frag(s_b, brow, k0 * 32 + kf, 128);
            acc[n0] = __builtin_amdgcn_mfma_f32_16x16x32_bf16(af[k0], bfg, acc[n0], 0, 0, 0);
        }
    }
    // residual + LN
    const int r0 = tok0 + w * 16 + (lane >> 4) * 4;
    const int cbase = lane & 15;
    #pragma unroll
    for (int n0 = 0; n0 < 8; ++n0)
        #pragma unroll
        for (int i = 0; i < 4; ++i)
            acc[n0][i] += z[(size_t)(r0 + i) * 128 + n0 * 16 + cbase];
    float s1[4] = {0,0,0,0}, s2[4] = {0,0,0,0};
    #pragma unroll
    for (int n0 = 0; n0 < 8; ++n0)
        #pragma unroll
        for (int i = 0; i < 4; ++i) { float v = acc[n0][i]; s1[i] += v; s2[i] += v * v; }
    #pragma unroll
    for (int m = 1; m < 16; m <<= 1)
        #pragma unroll
        for (int i = 0; i < 4; ++i) { s1[i] += __shfl_xor(s1[i], m); s2[i] += __shfl_xor(s2[i], m); }
    float gv[8], bev[8];
    #pragma unroll
    for (int n0 = 0; n0 < 8; ++n0) { gv[n0] = g[n0 * 16 + cbase]; bev[n0] = be[n0 * 16 + cbase]; }
    #pragma unroll
    for (int i = 0; i < 4; ++i) {
        float mu = s1[i] * (1.f / D_);
        float var = s2[i] * (1.f / D_) - mu * mu;
        float rstd = rsqrtf(var + 1e-5f);
        #pragma unroll
        for (int n0 = 0; n0 < 8; ++n0)
            z[(size_t)(r0 + i) * 128 + n0 * 16 + cbase] = (acc[n0][i] - mu) * rstd * gv[n0] + bev[n0];
    }
}

// ---------------------------------------------------------------------------
// z = LN(z + relu(z@W1+b1)@W2 + b2) : fused ff1+ff2 MFMA
__global__ __launch_bounds__(256) void ff_mfma(
    const float* __restrict__ zin, const short* __restrict__ W1T, const float* __restrict__ b1,
    const short* __restrict__ W2T, const float* __restrict__ b2,
    const float* __restrict__ g, const float* __restrict__ be, float* __restrict__ z)
{
    __shared__ short s_a[64 * 128];
    __shared__ short s_b[128 * 128];
    __shared__ short s_f[64 * 256];
    const int tid = threadIdx.x;
    const int w = tid >> 6, lane = tid & 63;
    const int tok0 = blockIdx.x * 64;
    stage_a(s_a, zin + (size_t)tok0 * 128, tid);
    __syncthreads();
    bf16x8 af[4];
    const int arow = w * 16 + (lane & 15);
    const int kf = (lane >> 4) * 8;
    #pragma unroll
    for (int k0 = 0; k0 < 4; ++k0) af[k0] = ld_frag(s_a, arow, k0 * 32 + kf, 128);

    // ---- ff1: 2 chunks of N=128, relu -> s_f bf16 [64][256] swizzled
    for (int ch = 0; ch < 2; ++ch) {
        __syncthreads();
        stage_b(s_b, W1T + ch * 128 * 128, tid);
        __syncthreads();
        #pragma unroll
        for (int n0 = 0; n0 < 8; ++n0) {
            const int ncol = ch * 128 + n0 * 16 + (lane & 15);
            const int brow = n0 * 16 + (lane & 15);
            float bv = b1[ncol];
            f32x4 acc = {bv, bv, bv, bv};
            #pragma unroll
            for (int k0 = 0; k0 < 4; ++k0) {
                bf16x8 bfg = ld_frag(s_b, brow, k0 * 32 + kf, 128);
                acc = __builtin_amdgcn_mfma_f32_16x16x32_bf16(af[k0], bfg, acc, 0, 0, 0);
            }
            #pragma unroll
            for (int i = 0; i < 4; ++i) {
                int row = w * 16 + (lane >> 4) * 4 + i;
                float v = fmaxf(acc[i], 0.f);
                s_f[row * 256 + (ncol ^ ((row & 7) << 3))] = (short)bf16_rne(v);
            }
        }
    }
    // ---- ff2: N=128, K=256 in 2 k-chunks
    f32x4 acc2[8];
    #pragma unroll
    for (int n0 = 0; n0 < 8; ++n0) {
        float bv = b2[n0 * 16 + (lane & 15)];
        acc2[n0] = (f32x4){bv, bv, bv, bv};
    }
    for (int kc = 0; kc < 2; ++kc) {
        __syncthreads();
        {   // stage W2T k-slice: 128 rows, k in [kc*128, kc*128+128), row stride 256
            #pragma unroll
            for (int it = 0; it < 8; ++it) {
                int c = it * 256 + tid;
                int row = c >> 4, ke = (c & 15) * 8;
                uint4 v = *(const uint4*)&W2T[row * 256 + kc * 128 + ke];
                *(uint4*)&s_b[row * 128 + (ke ^ ((row & 7) << 3))] = v;
            }
        }
        __syncthreads();
        bf16x8 af2[4];
        #pragma unroll
        for (int k0 = 0; k0 < 4; ++k0)
            af2[k0] = ld_frag(s_f, arow, kc * 128 + k0 * 32 + kf, 256);
        #pragma unroll
        for (int n0 = 0; n0 < 8; ++n0) {
            const int brow = n0 * 16 + (lane & 15);
            #pragma unroll
            for (int k0 = 0; k0 < 4; ++k0) {
                bf16x8 bfg = ld_frag(s_b, brow, k0 * 32 + kf, 128);
                acc2[n0] = __builtin_amdgcn_mfma_f32_16x16x32_bf16(af2[k0], bfg, acc2[n0], 0, 0, 0);
            }
        }
    }
    // residual + LN
    const int r0 = tok0 + w * 16 + (lane >> 4) * 4;
    const int cbase = lane & 15;
    #pragma unroll
    for (int n0 = 0; n0 < 8; ++n0)
        #pragma unroll
        for (int i = 0; i < 4; ++i)
            acc2[n0][i] += z[(size_t)(r0 + i) * 128 + n0 * 16 + cbase];
    float s1[4] = {0,0,0,0}, s2[4] = {0,0,0,0};
    #pragma unroll
    for (int n0 = 0; n0 < 8; ++n0)
        #pragma unroll
        for (int i = 0; i < 4; ++i) { float v = acc2[n0][i]; s1[i] += v; s2[i] += v * v; }
    #pragma unroll
    for (int m = 1; m < 16; m <<= 1)
        #pragma unroll
        for (int i = 0; i < 4; ++i) { s1[i] += __shfl_xor(s1[i], m); s2[i] += __shfl_xor(s2[i], m); }
    float gv[8], bev[8];
    #pragma unroll
    for (int n0 = 0; n0 < 8; ++n0) { gv[n0] = g[n0 * 16 + cbase]; bev[n0] = be[n0 * 16 + cbase]; }
    #pragma unroll
    for (int i = 0; i < 4; ++i) {
        float mu = s1[i] * (1.f / D_);
        float var = s2[i] * (1.f / D_) - mu * mu;
        float rstd = rsqrtf(var + 1e-5f);
        #pragma unroll
        for (int n0 = 0; n0 < 8; ++n0)
            z[(size_t)(r0 + i) * 128 + n0 * 16 + cbase] = (acc2[n0][i] - mu) * rstd * gv[n0] + bev[n0];
    }
}

// ---------------------------------------------------------------------------
// gcn = tanh(Anorm @ (x @ gcn_w + b)) -> gcn buffer [token][n*64+k]
__global__ __launch_bounds__(256) void gcn_kernel(
    const float* __restrict__ x, const float* __restrict__ gcn_w, const float* __restrict__ gcn_b,
    const float* __restrict__ ws, float* __restrict__ gcn)
{
    const int tid = threadIdx.x;
    const int tl = tid >> 6, k = tid & 63;
    const int tok = blockIdx.x * 4 + tl;
    __shared__ float s_x[4][N_ * F_];
    __shared__ float s_an[N_ * N_];
    if (tid < 4 * N_ * F_) ((float*)s_x)[tid] = x[(size_t)blockIdx.x * (4 * N_ * F_) + tid];
    if (tid < N_ * N_) s_an[tid] = ws[tid];
    __syncthreads();
    float w[F_];
    #pragma unroll
    for (int f = 0; f < F_; ++f) w[f] = gcn_w[f * 64 + k];
    const float bk = gcn_b[k];
    float xw[N_];
    #pragma unroll
    for (int n = 0; n < N_; ++n) {
        float acc = bk;
        #pragma unroll
        for (int f = 0; f < F_; ++f) acc += s_x[tl][n * F_ + f] * w[f];
        xw[n] = acc;
    }
    float* gout = gcn + (size_t)tok * (N_ * 64);
    #pragma unroll
    for (int n = 0; n < N_; ++n) {
        float s = 0.f;
        #pragma unroll
        for (int j = 0; j < N_; ++j) s += s_an[n * N_ + j] * xw[j];
        float ax = fabsf(s);
        float e = __expf(2.f * ax);
        float t = 1.f - 2.f / (e + 1.f);
        gout[n * 64 + k] = copysignf(t, s);
    }
}

// ---------------------------------------------------------------------------
// GAT -> LN -> mean -> +PE (2 tokens per 256-thread block)
__global__ __launch_bounds__(256, 4) void gat_kernel(
    const float* __restrict__ gcn, const float* __restrict__ gat_w,
    const float* __restrict__ a_src, const float* __restrict__ a_dst,
    const float* __restrict__ gat_b, const float* __restrict__ gln_g, const float* __restrict__ gln_b,
    const float* __restrict__ ws, float* __restrict__ z, int E2)
{
    const int tid = threadIdx.x;
    const int tl  = tid >> 7;
    const int d   = tid & 127;
    const int wv  = (tid >> 6) & 1;
    const int tok = blockIdx.x * 2 + tl;
    const int t   = tok % T_;

    __shared__ float s_gcn[2][N_][64];
    __shared__ float s_h[2][N_][D_];
    __shared__ float s_as[2][N_][HH_], s_ad[2][N_][HH_];
    __shared__ float s_alpha[2][E2MAX][HH_];
    __shared__ int   s_src[E2MAX], s_csr_off[N_ + 1], s_csr_e[E2MAX];
    __shared__ float s_red[2][N_][2][2];

    const int* wsi = (const int*)ws;
    if (tid < E2) { s_src[tid] = wsi[32 + tid]; s_csr_e[tid] = wsi[104 + tid]; }
    if (tid < N_ + 1) s_csr_off[tid] = wsi[96 + tid];
    {
        const float* g0 = gcn + (size_t)tok * (N_ * 64);
        for (int i = d; i < N_ * 64; i += 128) ((float*)s_gcn[tl])[i] = g0[i];
    }
    __syncthreads();

    float hh[N_] = {0.f, 0.f, 0.f, 0.f, 0.f};
    for (int k4 = 0; k4 < 64; k4 += 4) {
        float4 g[N_];
        #pragma unroll
        for (int n = 0; n < N_; ++n) g[n] = *(const float4*)&s_gcn[tl][n][k4];
        #pragma unroll
        for (int kk = 0; kk < 4; ++kk) {
            float wval = gat_w[(k4 + kk) * D_ + d];
            #pragma unroll
            for (int n = 0; n < N_; ++n) hh[n] += ((const float*)&g[n])[kk] * wval;
        }
    }
    #pragma unroll
    for (int n = 0; n < N_; ++n) s_h[tl][n][d] = hh[n];

    const float asd = a_src[d], add_ = a_dst[d];
    float va[N_], vb[N_];
    #pragma unroll
    for (int n = 0; n < N_; ++n) { va[n] = hh[n] * asd; vb[n] = hh[n] * add_; }
    #pragma unroll
    for (int m = 16; m >= 1; m >>= 1) {
        #pragma unroll
        for (int n = 0; n < N_; ++n) { va[n] += __shfl_xor(va[n], m); vb[n] += __shfl_xor(vb[n], m); }
    }
    if ((d & 31) == 0) {
        int head = d >> 5;
        #pragma unroll
        for (int n = 0; n < N_; ++n) { s_as[tl][n][head] = va[n]; s_ad[tl][n][head] = vb[n]; }
    }
    __syncthreads();

    if (tid < 2 * N_ * HH_) {
        int tg = tid / (N_ * HH_), idx = tid % (N_ * HH_);
        int dn = idx >> 2, head = idx & 3;
        int j0 = s_csr_off[dn], j1 = s_csr_off[dn + 1];
        float adv = s_ad[tg][dn][head];
        float mx = -1e30f;
        for (int j = j0; j < j1; ++j) {
            int e = s_csr_e[j];
            float ev = s_as[tg][s_src[e]][head] + adv;
            ev = ev > 0.f ? ev : 0.2f * ev;
            mx = fmaxf(mx, ev);
        }
        float den = 0.f;
        for (int j = j0; j < j1; ++j) {
            int e = s_csr_e[j];
            float ev = s_as[tg][s_src[e]][head] + adv;
            ev = ev > 0.f ? ev : 0.2f * ev;
            float ex = __expf(ev - mx);
            den += ex;
            s_alpha[tg][e][head] = ex;
        }
        float r = 1.f / den;
        for (int j = j0; j < j1; ++j) s_alpha[tg][s_csr_e[j]][head] *= r;
    }
    __syncthreads();

    const int head = d >> 5;
    const float gb = gat_b[d];
    float val[N_];
    #pragma unroll
    for (int n = 0; n < N_; ++n) {
        float agg = 0.f;
        int j0 = s_csr_off[n], j1 = s_csr_off[n + 1];
        for (int j = j0; j < j1; ++j) {
            int e = s_csr_e[j];
            agg += s_alpha[tl][e][head] * s_h[tl][s_src[e]][d];
        }
        val[n] = agg + gb;
    }
    float sa[N_], sq[N_];
    #pragma unroll
    for (int n = 0; n < N_; ++n) { sa[n] = val[n]; sq[n] = val[n] * val[n]; }
    #pragma unroll
    for (int m = 32; m >= 1; m >>= 1) {
        #pragma unroll
        for (int n = 0; n < N_; ++n) { sa[n] += __shfl_xor(sa[n], m); sq[n] += __shfl_xor(sq[n], m); }
    }
    if ((tid & 63) == 0) {
        #pragma unroll
        for (int n = 0; n < N_; ++n) { s_red[tl][n][wv][0] = sa[n]; s_red[tl][n][wv][1] = sq[n]; }
    }
    __syncthreads();

    float zacc = 0.f;
    const float gg = gln_g[d], gbb = gln_b[d];
    #pragma unroll
    for (int n = 0; n < N_; ++n) {
        float sum = s_red[tl][n][0][0] + s_red[tl][n][1][0];
        float sqq = s_red[tl][n][0][1] + s_red[tl][n][1][1];
        float mu = sum * (1.f / D_);
        float var = sqq * (1.f / D_) - mu * mu;
        float rstd = rsqrtf(var + 1e-5f);
        zacc += (val[n] - mu) * rstd * gg + gbb;
    }
    zacc *= (1.f / N_);

    const float cpe = -9.210340371976184f / (float)D_;
    float dv = __expf((float)(d & ~1) * cpe);
    float ang = (float)t * dv;
    float pe = (d & 1) ? __cosf(ang) : __sinf(ang);
    z[(size_t)tok * D_ + d] = zacc + pe;
}

// ---------------------------------------------------------------------------
// full attention for one (batch, head): scores + softmax + PV, all in LDS (fp32)
__global__ __launch_bounds__(256) void attn_kernel(
    const float* __restrict__ qkv, float* __restrict__ obuf)
{
    const int bh = blockIdx.x;
    const int b = bh >> 2, h = bh & 3;
    __shared__ float s_q[T_][33], s_k[T_][33], s_v[T_][33];
    __shared__ float s_p[T_][73];
    const int tid = threadIdx.x;
    const float* base = qkv + (size_t)b * T_ * 384 + h * 32;
    for (int idx = tid; idx < T_ * 32; idx += 256) {
        int i = idx >> 5, c = idx & 31;
        s_q[i][c] = base[i * 384 + c];
        s_k[i][c] = base[i * 384 + 128 + c];
        s_v[i][c] = base[i * 384 + 256 + c];
    }
    __syncthreads();
    const float scale = 0.17677669529663687f;
    for (int idx = tid; idx < T_ * T_; idx += 256) {
        int i = idx / T_, j = idx - i * T_;
        float s = 0.f;
        #pragma unroll
        for (int c = 0; c < 32; ++c) s += s_q[i][c] * s_k[j][c];
        s_p[i][j] = s * scale;
    }
    __syncthreads();
    if (tid < T_) {
        float mx = -1e30f;
        for (int j = 0; j < T_; ++j) mx = fmaxf(mx, s_p[tid][j]);
        float den = 0.f;
        for (int j = 0; j < T_; ++j) { float e = __expf(s_p[tid][j] - mx); s_p[tid][j] = e; den += e; }
        float r = 1.f / den;
        for (int j = 0; j < T_; ++j) s_p[tid][j] *= r;
    }
    __syncthreads();
    for (int idx = tid; idx < T_ * 32; idx += 256) {
        int i = idx >> 5, c = idx & 31;
        float o = 0.f;
        for (int j = 0; j < T_; ++j) o += s_p[i][j] * s_v[j][c];
        obuf[(size_t)(b * T_ + i) * D_ + h * 32 + c] = o;
    }
}

// ---------------------------------------------------------------------------
__global__ __launch_bounds__(64) void heads_kernel(
    const float* __restrict__ z, const float* __restrict__ hw1, const float* __restrict__ hb1,
    const float* __restrict__ hw2, const float* __restrict__ hb2, float* __restrict__ out)
{
    const int k = blockIdx.x >> 8;
    const int b = blockIdx.x & 255;
    const int tid = threadIdx.x;
    __shared__ float s_last[D_];
    __shared__ float s_h1[64];
    const float* zr = z + (size_t)(b * T_ + (T_ - 1)) * D_;
    s_last[tid] = zr[tid];
    s_last[tid + 64] = zr[tid + 64];
    __syncthreads();
    float acc = hb1[k * 64 + tid];
    const float* w1 = hw1 + (size_t)k * D_ * 64;
    for (int dd = 0; dd < D_; ++dd) acc += s_last[dd] * w1[dd * 64 + tid];
    s_h1[tid] = fmaxf(acc, 0.f);
    __syncthreads();
    if (tid < 5) {
        float o = hb2[k * 5 + tid];
        const float* w2 = hw2 + (size_t)k * 64 * 5;
        for (int j = 0; j < 64; ++j) o += s_h1[j] * w2[j * 5 + tid];
        out[(size_t)k * (B_ * 5) + b * 5 + tid] = o;
    }
}

// ---------------------------------------------------------------------------
extern "C" void kernel_launch(void* const* d_in, const int* in_sizes, int n_in,
                              void* d_out, int out_size, void* d_ws, size_t ws_size,
                              hipStream_t stream) {
    const float* x      = (const float*)d_in[0];
    const int*   ei     = (const int*)  d_in[1];
    const float* gcn_w  = (const float*)d_in[2];
    const float* gcn_b  = (const float*)d_in[3];
    const float* gat_w  = (const float*)d_in[4];
    const float* a_src  = (const float*)d_in[5];
    const float* a_dst  = (const float*)d_in[6];
    const float* gat_b  = (const float*)d_in[7];
    const float* gln_g  = (const float*)d_in[8];
    const float* gln_b  = (const float*)d_in[9];
    const float* tw_qkv = (const float*)d_in[10];
    const float* tb_qkv = (const float*)d_in[11];
    const float* tw_o   = (const float*)d_in[12];
    const float* tb_o   = (const float*)d_in[13];
    const float* ln1_g  = (const float*)d_in[14];
    const float* ln1_b  = (const float*)d_in[15];
    const float* w_ff1  = (const float*)d_in[16];
    const float* b_ff1  = (const float*)d_in[17];
    const float* w_ff2  = (const float*)d_in[18];
    const float* b_ff2  = (const float*)d_in[19];
    const float* ln2_g  = (const float*)d_in[20];
    const float* ln2_b  = (const float*)d_in[21];
    const float* hw1    = (const float*)d_in[22];
    const float* hb1    = (const float*)d_in[23];
    const float* hw2    = (const float*)d_in[24];
    const float* hb2    = (const float*)d_in[25];
    float* out = (float*)d_out;
    float* ws  = (float*)d_ws;

    float* z    = ws + WS_Z;
    float* qkv  = ws + WS_QKV;
    float* obuf = ws + WS_OBUF;
    float* gcn  = ws + WS_QKV;           // aliases qkv region (dead before layer 0)
    short* wbf  = (short*)(ws + WS_WBF); // bf16 weights

    const int E = in_sizes[1] / 2;   // 20
    const int E2 = E + N_;           // 25

    setup_kernel<<<1, 64, 0, stream>>>(ei, ws, E);
    prep_kernel<<<96, 256, 0, stream>>>(tw_qkv, tw_o, w_ff1, w_ff2, wbf);
    gcn_kernel<<<BT_ / 4, 256, 0, stream>>>(x, gcn_w, gcn_b, ws, gcn);
    gat_kernel<<<BT_ / 2, 256, 0, stream>>>(gcn, gat_w, a_src, a_dst, gat_b,
                                            gln_g, gln_b, ws, z, E2);
    for (int i = 0; i < 3; ++i) {
        qkv_mfma<<<BT_ / 64, 256, 0, stream>>>(z, wbf + WOFF_QKV(i),
                                               tb_qkv + (size_t)i * 3 * D_, qkv);
        attn_kernel<<<B_ * HH_, 256, 0, stream>>>(qkv, obuf);
        oproj_mfma<<<BT_ / 64, 256, 0, stream>>>(obuf, wbf + WOFF_O(i),
                                                 tb_o + (size_t)i * D_,
                                                 ln1_g + (size_t)i * D_, ln1_b + (size_t)i * D_, z);
        ff_mfma<<<BT_ / 64, 256, 0, stream>>>(z, wbf + WOFF_FF1(i), b_ff1 + (size_t)i * FF_,
                                              wbf + WOFF_FF2(i), b_ff2 + (size_t)i * D_,
                                              ln2_g + (size_t)i * D_, ln2_b + (size_t)i * D_, z);
    }
    heads_kernel<<<6 * B_, 64, 0, stream>>>(z, hw1, hb1, hw2, hb2, out);
}

// Round 5
// 491.514 us; speedup vs baseline: 2.6709x; 1.0292x over previous
//
#include <hip/hip_runtime.h>
#include <hip/hip_bf16.h>

// Problem constants (fixed by the reference)
#define B_  256
#define T_  72
#define N_  5
#define F_  10
#define D_  128
#define HH_ 4
#define CC_ 32
#define FF_ 256
#define BT_ (B_*T_)   // 18432
#define E2MAX 32

// ---------------- ws layout (float offsets) ----------------
#define WS_Z    256
#define WS_QKV  (WS_Z + BT_*D_)
#define WS_OBUF (WS_QKV + BT_*3*D_)
#define WS_WBF  (WS_OBUF + BT_*D_)      // bf16 weight region

// bf16 weight offsets (in shorts, from WS_WBF base)
#define WOFF_QKV(i)  ((i)*49152)                 // [384][128]
#define WOFF_O(i)    (147456 + (i)*16384)        // [128][128]
#define WOFF_FF1(i)  (196608 + (i)*32768)        // [256][128]
#define WOFF_FF2(i)  (294912 + (i)*32768)        // [128][256]
#define WOFF_GATW    393216                      // [128][64]

typedef __attribute__((ext_vector_type(8))) short bf16x8;
typedef __attribute__((ext_vector_type(4))) float f32x4;

__device__ __forceinline__ unsigned short bf16_rne(float x) {
    unsigned u = __float_as_uint(x);
    unsigned r = (u + 0x7FFFu + ((u >> 16) & 1u)) >> 16;
    return (unsigned short)r;
}
__device__ __forceinline__ unsigned bf16pk(float a, float b) {
    return (unsigned)bf16_rne(a) | ((unsigned)bf16_rne(b) << 16);
}
__device__ __forceinline__ float bf2f(short s) {
    return __uint_as_float(((unsigned)(unsigned short)s) << 16);
}

// ---------------------------------------------------------------------------
__global__ void setup_kernel(const int* __restrict__ ei, float* __restrict__ ws, int E) {
    if (threadIdx.x != 0 || blockIdx.x != 0) return;
    int* wsi = (int*)ws;
    const int N = N_;
    int E2 = E + N;
    int src2[E2MAX], dst2[E2MAX];
    for (int e = 0; e < E; ++e) { src2[e] = ei[e]; dst2[e] = ei[E + e]; }
    for (int n = 0; n < N; ++n) { src2[E + n] = n; dst2[E + n] = n; }
    float A[N_ * N_];
    for (int i = 0; i < N * N; ++i) A[i] = 0.f;
    for (int e = 0; e < E2; ++e) A[dst2[e] * N + src2[e]] += 1.f;
    float dinv[N_];
    for (int n = 0; n < N; ++n) {
        float s = 0.f;
        for (int j = 0; j < N; ++j) s += A[n * N + j];
        dinv[n] = (s > 0.f) ? rsqrtf(s) : 0.f;
    }
    for (int n = 0; n < N; ++n)
        for (int j = 0; j < N; ++j)
            ws[n * N + j] = dinv[n] * A[n * N + j] * dinv[j];
    int cnt[N_];
    for (int n = 0; n < N; ++n) cnt[n] = 0;
    for (int e = 0; e < E2; ++e) cnt[dst2[e]]++;
    int off = 0;
    for (int n = 0; n < N; ++n) { wsi[96 + n] = off; off += cnt[n]; }
    wsi[96 + N] = off;
    int cur[N_];
    for (int n = 0; n < N; ++n) cur[n] = wsi[96 + n];
    for (int e = 0; e < E2; ++e) wsi[104 + cur[dst2[e]]++] = e;
    for (int e = 0; e < E2; ++e) { wsi[32 + e] = src2[e]; wsi[64 + e] = dst2[e]; }
}

// ---------------------------------------------------------------------------
// Weight prep: transpose R x C fp32 -> [C][R] bf16 into ws.
// blocks 0..95: transformer weights; 96..97: gat_w [64][128] -> [128][64]
__global__ __launch_bounds__(256) void prep_kernel(
    const float* __restrict__ tw_qkv, const float* __restrict__ tw_o,
    const float* __restrict__ w_ff1, const float* __restrict__ w_ff2,
    const float* __restrict__ gat_w, short* __restrict__ wbf)
{
    __shared__ float s_t[64][65];
    const int tid = threadIdx.x;
    int t = blockIdx.x;
    const float* src; short* dst; int R, C, tr, tc;
    if (t >= 96) { int q = t - 96; src = gat_w; dst = wbf + WOFF_GATW; R = 64; C = 128; tr = 0; tc = q; }
    else {
        int layer = t / 32, r32 = t % 32;
        if (r32 < 12)      { src = tw_qkv + layer * (128*384); dst = wbf + WOFF_QKV(layer); R = 128; C = 384; tr = r32 / 6;  tc = r32 % 6; }
        else if (r32 < 16) { int q = r32 - 12; src = tw_o + layer * 16384; dst = wbf + WOFF_O(layer);  R = 128; C = 128; tr = q >> 1; tc = q & 1; }
        else if (r32 < 24) { int q = r32 - 16; src = w_ff1 + layer * 32768; dst = wbf + WOFF_FF1(layer); R = 128; C = 256; tr = q >> 2; tc = q & 3; }
        else               { int q = r32 - 24; src = w_ff2 + layer * 32768; dst = wbf + WOFF_FF2(layer); R = 256; C = 128; tr = q >> 1; tc = q & 1; }
    }
    #pragma unroll
    for (int it = 0; it < 16; ++it) {
        int e = it * 256 + tid;
        int r = e >> 6, c = e & 63;
        s_t[r][c] = src[(size_t)(tr*64 + r) * C + tc*64 + c];
    }
    __syncthreads();
    #pragma unroll
    for (int it = 0; it < 16; ++it) {
        int e = it * 256 + tid;
        int c = e >> 6, r = e & 63;
        dst[(size_t)(tc*64 + c) * R + tr*64 + r] = (short)bf16_rne(s_t[r][c]);
    }
}

// ---------------------------------------------------------------------------
// MFMA helpers: A stored [rows][K] bf16 LDS, swizzle kelem ^ ((row&7)<<3).
__device__ __forceinline__ bf16x8 ld_frag(const short* s, int row, int kbase, int ldk) {
    return *(const bf16x8*)&s[row * ldk + (kbase ^ ((row & 7) << 3))];
}
// stage 64x128 fp32 -> bf16 swizzled LDS
__device__ __forceinline__ void stage_a(short* s_a, const float* __restrict__ src, int tid) {
    const float2* s2 = (const float2*)src;
    #pragma unroll
    for (int it = 0; it < 16; ++it) {
        int i2 = it * 256 + tid;
        int row = i2 >> 6, ke = (i2 & 63) * 2;
        float2 v = s2[i2];
        *(unsigned*)&s_a[row * 128 + (ke ^ ((row & 7) << 3))] = bf16pk(v.x, v.y);
    }
}
// stage 128 rows x 128 k of contiguous bf16 [N][128] -> swizzled LDS
__device__ __forceinline__ void stage_b(short* s_b, const short* __restrict__ src, int tid) {
    const uint4* s4 = (const uint4*)src;
    #pragma unroll
    for (int it = 0; it < 8; ++it) {
        int c = it * 256 + tid;
        int row = c >> 4, ke = (c & 15) * 8;
        *(uint4*)&s_b[row * 128 + (ke ^ ((row & 7) << 3))] = s4[c];
    }
}

// ---------------------------------------------------------------------------
// Fused graph stage: GCN -> tanh -> h(MFMA) -> GAT softmax/agg -> LN -> mean -> +PE
// block = 16 tokens, 256 threads (4 waves); everything in LDS.
__global__ __launch_bounds__(256) void graph_fused(
    const float* __restrict__ x, const float* __restrict__ gcn_w, const float* __restrict__ gcn_b,
    const float* __restrict__ a_src, const float* __restrict__ a_dst,
    const float* __restrict__ gat_b, const float* __restrict__ gln_g, const float* __restrict__ gln_b,
    const float* __restrict__ ws, const short* __restrict__ gwT, float* __restrict__ z, int E2)
{
    __shared__ float s_x[16 * 50];
    __shared__ float s_an[25];
    __shared__ int   s_src[E2MAX], s_csr_off[N_ + 1], s_csr_e[E2MAX];
    __shared__ short s_gcn[80 * 64];     // bf16, swizzled
    __shared__ short s_gw[128 * 64];     // bf16, swizzled [col][k]
    __shared__ short s_h[80 * 136];      // bf16 h, padded rows
    __shared__ float s_as[80][4], s_ad[80][4];
    __shared__ float s_alpha[16][E2MAX][4];

    const int tid = threadIdx.x;
    const int tok0 = blockIdx.x * 16;
    const int* wsi = (const int*)ws;

    // ---- stage x, anorm, csr, gat_w
    for (int i = tid; i < 16 * 50; i += 256) s_x[i] = x[(size_t)tok0 * 50 + i];
    if (tid < 25) s_an[tid] = ws[tid];
    if (tid < E2) { s_src[tid] = wsi[32 + tid]; s_csr_e[tid] = wsi[104 + tid]; }
    if (tid < N_ + 1) s_csr_off[tid] = wsi[96 + tid];
    {
        const uint4* g4 = (const uint4*)gwT;
        #pragma unroll
        for (int it = 0; it < 4; ++it) {          // FIX: 4 iters = 1024 uint4 (all 128 rows)
            int e8 = it * 256 + tid;              // uint4 index: 8 shorts each
            int row = e8 >> 3, ke = (e8 & 7) * 8;
            *(uint4*)&s_gw[row * 64 + (ke ^ ((row & 7) << 3))] = g4[e8];
        }
    }
    __syncthreads();

    // ---- GCN: 512 (token,k-pair) items over 2 iterations
    #pragma unroll
    for (int it = 0; it < 2; ++it) {
        int idx = it * 256 + tid;
        int tl = idx >> 5, kp = idx & 31;
        int k0 = kp * 2;
        float w0[F_], w1[F_];
        #pragma unroll
        for (int f = 0; f < F_; ++f) { w0[f] = gcn_w[f * 64 + k0]; w1[f] = gcn_w[f * 64 + k0 + 1]; }
        float b0 = gcn_b[k0], b1 = gcn_b[k0 + 1];
        float xw0[N_], xw1[N_];
        #pragma unroll
        for (int n = 0; n < N_; ++n) {
            float a0 = b0, a1 = b1;
            #pragma unroll
            for (int f = 0; f < F_; ++f) {
                float xv = s_x[tl * 50 + n * 10 + f];
                a0 += xv * w0[f]; a1 += xv * w1[f];
            }
            xw0[n] = a0; xw1[n] = a1;
        }
        #pragma unroll
        for (int n = 0; n < N_; ++n) {
            float s0 = 0.f, s1 = 0.f;
            #pragma unroll
            for (int j = 0; j < N_; ++j) { float an = s_an[n * 5 + j]; s0 += an * xw0[j]; s1 += an * xw1[j]; }
            float e0 = __expf(2.f * fabsf(s0)), e1 = __expf(2.f * fabsf(s1));
            float t0 = copysignf(1.f - 2.f / (e0 + 1.f), s0);
            float t1 = copysignf(1.f - 2.f / (e1 + 1.f), s1);
            int row = tl * 5 + n;
            *(unsigned*)&s_gcn[row * 64 + (k0 ^ ((row & 7) << 3))] = bf16pk(t0, t1);
        }
    }
    __syncthreads();

    // ---- h = gcn @ gat_w via MFMA; wave w owns head w (cols 32w..32w+31)
    const int w = tid >> 6, lane = tid & 63;
    const int c = lane & 15, g = lane >> 4;
    const int kf = g * 8;
    bf16x8 bfr[2][2];
    #pragma unroll
    for (int nn = 0; nn < 2; ++nn)
        #pragma unroll
        for (int k0 = 0; k0 < 2; ++k0)
            bfr[nn][k0] = ld_frag(s_gw, w * 32 + nn * 16 + c, k0 * 32 + kf, 64);
    const float as0 = a_src[w * 32 + c],      as1 = a_src[w * 32 + 16 + c];
    const float ad0 = a_dst[w * 32 + c],      ad1 = a_dst[w * 32 + 16 + c];
    #pragma unroll
    for (int m = 0; m < 5; ++m) {
        bf16x8 af0 = ld_frag(s_gcn, m * 16 + c, kf, 64);
        bf16x8 af1 = ld_frag(s_gcn, m * 16 + c, 32 + kf, 64);
        f32x4 a0 = {0,0,0,0}, a1 = {0,0,0,0};
        a0 = __builtin_amdgcn_mfma_f32_16x16x32_bf16(af0, bfr[0][0], a0, 0, 0, 0);
        a0 = __builtin_amdgcn_mfma_f32_16x16x32_bf16(af1, bfr[0][1], a0, 0, 0, 0);
        a1 = __builtin_amdgcn_mfma_f32_16x16x32_bf16(af0, bfr[1][0], a1, 0, 0, 0);
        a1 = __builtin_amdgcn_mfma_f32_16x16x32_bf16(af1, bfr[1][1], a1, 0, 0, 0);
        float ps[4], pd[4];
        #pragma unroll
        for (int i = 0; i < 4; ++i) {
            int row = m * 16 + g * 4 + i;
            s_h[row * 136 + w * 32 + c]      = (short)bf16_rne(a0[i]);
            s_h[row * 136 + w * 32 + 16 + c] = (short)bf16_rne(a1[i]);
            ps[i] = a0[i] * as0 + a1[i] * as1;
            pd[i] = a0[i] * ad0 + a1[i] * ad1;
        }
        #pragma unroll
        for (int mm = 1; mm < 16; mm <<= 1)
            #pragma unroll
            for (int i = 0; i < 4; ++i) { ps[i] += __shfl_xor(ps[i], mm); pd[i] += __shfl_xor(pd[i], mm); }
        if (c == 0) {
            #pragma unroll
            for (int i = 0; i < 4; ++i) {
                int row = m * 16 + g * 4 + i;
                s_as[row][w] = ps[i]; s_ad[row][w] = pd[i];
            }
        }
    }
    __syncthreads();

    // ---- attention coefficients: 64 threads = (16 tokens x 4 heads)
    if (tid < 64) {
        int tl = tid >> 2, head = tid & 3;
        for (int dn = 0; dn < N_; ++dn) {
            int j0 = s_csr_off[dn], j1 = s_csr_off[dn + 1];
            float adv = s_ad[tl * 5 + dn][head];
            float mx = -1e30f;
            for (int j = j0; j < j1; ++j) {
                int e = s_csr_e[j];
                float ev = s_as[tl * 5 + s_src[e]][head] + adv;
                ev = ev > 0.f ? ev : 0.2f * ev;
                mx = fmaxf(mx, ev);
            }
            float den = 0.f;
            for (int j = j0; j < j1; ++j) {
                int e = s_csr_e[j];
                float ev = s_as[tl * 5 + s_src[e]][head] + adv;
                ev = ev > 0.f ? ev : 0.2f * ev;
                float ex = __expf(ev - mx);
                den += ex;
                s_alpha[tl][e][head] = ex;
            }
            float r = 1.f / den;
            for (int j = j0; j < j1; ++j) s_alpha[tl][s_csr_e[j]][head] *= r;
        }
    }
    __syncthreads();

    // ---- aggregate + gat_b + LN per node + mean + PE; wave w: tokens {w,w+4,w+8,w+12}
    const float gb0 = gat_b[lane],      gb1 = gat_b[lane + 64];
    const float gg0 = gln_g[lane],      gg1 = gln_g[lane + 64];
    const float gB0 = gln_b[lane],      gB1 = gln_b[lane + 64];
    const int h0 = lane >> 5, h1 = 2 + (lane >> 5);
    const float cpe = -9.210340371976184f / (float)D_;
    const float dv0 = __expf((float)(lane & ~1) * cpe);
    const float dv1 = __expf((float)((lane + 64) & ~1) * cpe);
    for (int tt = 0; tt < 4; ++tt) {
        int tl = w + tt * 4;
        int tok = tok0 + tl;
        float v0[N_], v1[N_];
        #pragma unroll
        for (int n = 0; n < N_; ++n) {
            float acc0 = 0.f, acc1 = 0.f;
            int j0 = s_csr_off[n], j1 = s_csr_off[n + 1];
            for (int j = j0; j < j1; ++j) {
                int e = s_csr_e[j];
                int rb = (tl * 5 + s_src[e]) * 136;
                acc0 += s_alpha[tl][e][h0] * bf2f(s_h[rb + lane]);
                acc1 += s_alpha[tl][e][h1] * bf2f(s_h[rb + lane + 64]);
            }
            v0[n] = acc0 + gb0; v1[n] = acc1 + gb1;
        }
        float r1[N_], r2[N_];
        #pragma unroll
        for (int n = 0; n < N_; ++n) { r1[n] = v0[n] + v1[n]; r2[n] = v0[n]*v0[n] + v1[n]*v1[n]; }
        #pragma unroll
        for (int mm = 1; mm < 64; mm <<= 1)
            #pragma unroll
            for (int n = 0; n < N_; ++n) { r1[n] += __shfl_xor(r1[n], mm); r2[n] += __shfl_xor(r2[n], mm); }
        float z0 = 0.f, z1 = 0.f;
        #pragma unroll
        for (int n = 0; n < N_; ++n) {
            float mu = r1[n] * (1.f / D_);
            float var = r2[n] * (1.f / D_) - mu * mu;
            float rstd = rsqrtf(var + 1e-5f);
            z0 += (v0[n] - mu) * rstd * gg0 + gB0;
            z1 += (v1[n] - mu) * rstd * gg1 + gB1;
        }
        z0 *= (1.f / N_); z1 *= (1.f / N_);
        int t = tok % T_;
        float ang0 = (float)t * dv0, ang1 = (float)t * dv1;
        z0 += (lane & 1) ? __cosf(ang0) : __sinf(ang0);
        z1 += (lane & 1) ? __cosf(ang1) : __sinf(ang1);
        z[(size_t)tok * D_ + lane] = z0;
        z[(size_t)tok * D_ + 64 + lane] = z1;
    }
}

// ---------------------------------------------------------------------------
// qkv = z @ Wqkv + b : M-tile 64, 4 waves, 3 N-chunks of 128
__global__ __launch_bounds__(256) void qkv_mfma(
    const float* __restrict__ z, const short* __restrict__ WT, const float* __restrict__ bias,
    float* __restrict__ qkv)
{
    __shared__ short s_a[64 * 128];
    __shared__ short s_b[128 * 128];
    const int tid = threadIdx.x;
    const int w = tid >> 6, lane = tid & 63;
    const int tok0 = blockIdx.x * 64;
    stage_a(s_a, z + (size_t)tok0 * 128, tid);
    __syncthreads();
    bf16x8 af[4];
    const int arow = w * 16 + (lane & 15);
    const int kf = (lane >> 4) * 8;
    #pragma unroll
    for (int k0 = 0; k0 < 4; ++k0) af[k0] = ld_frag(s_a, arow, k0 * 32 + kf, 128);

    for (int ch = 0; ch < 3; ++ch) {
        __syncthreads();
        stage_b(s_b, WT + ch * 128 * 128, tid);
        __syncthreads();
        #pragma unroll
        for (int n0 = 0; n0 < 8; ++n0) {
            const int ncol = ch * 128 + n0 * 16 + (lane & 15);
            const int brow = n0 * 16 + (lane & 15);
            float bv = bias[ncol];
            f32x4 acc = {bv, bv, bv, bv};
            #pragma unroll
            for (int k0 = 0; k0 < 4; ++k0) {
                bf16x8 bfg = ld_frag(s_b, brow, k0 * 32 + kf, 128);
                acc = __builtin_amdgcn_mfma_f32_16x16x32_bf16(af[k0], bfg, acc, 0, 0, 0);
            }
            const int r0 = tok0 + w * 16 + (lane >> 4) * 4;
            #pragma unroll
            for (int i = 0; i < 4; ++i)
                qkv[(size_t)(r0 + i) * 384 + ncol] = acc[i];
        }
    }
}

// ---------------------------------------------------------------------------
// full attention for one (batch, head): scores + softmax + PV, all in LDS (fp32)
__global__ __launch_bounds__(256) void attn_kernel(
    const float* __restrict__ qkv, float* __restrict__ obuf)
{
    const int bh = blockIdx.x;
    const int b = bh >> 2, h = bh & 3;
    __shared__ float s_q[T_][33], s_k[T_][33], s_v[T_][33];
    __shared__ float s_p[T_][73];
    const int tid = threadIdx.x;
    const float* base = qkv + (size_t)b * T_ * 384 + h * 32;
    for (int idx = tid; idx < T_ * 32; idx += 256) {
        int i = idx >> 5, c = idx & 31;
        s_q[i][c] = base[i * 384 + c];
        s_k[i][c] = base[i * 384 + 128 + c];
        s_v[i][c] = base[i * 384 + 256 + c];
    }
    __syncthreads();
    const float scale = 0.17677669529663687f;
    for (int idx = tid; idx < T_ * T_; idx += 256) {
        int i = idx / T_, j = idx - i * T_;
        float s = 0.f;
        #pragma unroll
        for (int c = 0; c < 32; ++c) s += s_q[i][c] * s_k[j][c];
        s_p[i][j] = s * scale;
    }
    __syncthreads();
    if (tid < T_) {
        float mx = -1e30f;
        for (int j = 0; j < T_; ++j) mx = fmaxf(mx, s_p[tid][j]);
        float den = 0.f;
        for (int j = 0; j < T_; ++j) { float e = __expf(s_p[tid][j] - mx); s_p[tid][j] = e; den += e; }
        float r = 1.f / den;
        for (int j = 0; j < T_; ++j) s_p[tid][j] *= r;
    }
    __syncthreads();
    for (int idx = tid; idx < T_ * 32; idx += 256) {
        int i = idx >> 5, c = idx & 31;
        float o = 0.f;
        for (int j = 0; j < T_; ++j) o += s_p[i][j] * s_v[j][c];
        obuf[(size_t)(b * T_ + i) * D_ + h * 32 + c] = o;
    }
}

// ---------------------------------------------------------------------------
// Fused: z1 = LN1(z + obuf@Wo + bo); z = LN2(z1 + relu(z1@W1+b1)@W2 + b2)
__global__ __launch_bounds__(256) void oproj_ff_mfma(
    const float* __restrict__ obuf, const short* __restrict__ WoT, const float* __restrict__ bo,
    const float* __restrict__ g1, const float* __restrict__ be1,
    const short* __restrict__ W1T, const float* __restrict__ b1,
    const short* __restrict__ W2T, const float* __restrict__ b2,
    const float* __restrict__ g2, const float* __restrict__ be2,
    float* __restrict__ z)
{
    __shared__ short s_a[64 * 128];
    __shared__ short s_b[128 * 128];
    __shared__ short s_f[64 * 256];
    const int tid = threadIdx.x;
    const int w = tid >> 6, lane = tid & 63;
    const int tok0 = blockIdx.x * 64;
    const int cbase = lane & 15;
    const int arow = w * 16 + cbase;
    const int kf = (lane >> 4) * 8;
    const int r0 = tok0 + w * 16 + (lane >> 4) * 4;
    const int lrow0 = w * 16 + (lane >> 4) * 4;

    stage_a(s_a, obuf + (size_t)tok0 * 128, tid);
    stage_b(s_b, WoT, tid);
    __syncthreads();
    bf16x8 af[4];
    #pragma unroll
    for (int k0 = 0; k0 < 4; ++k0) af[k0] = ld_frag(s_a, arow, k0 * 32 + kf, 128);

    // ---- o-proj
    f32x4 acc[8];
    #pragma unroll
    for (int n0 = 0; n0 < 8; ++n0) {
        float bv = bo[n0 * 16 + cbase];
        acc[n0] = (f32x4){bv, bv, bv, bv};
        const int brow = n0 * 16 + cbase;
        #pragma unroll
        for (int k0 = 0; k0 < 4; ++k0) {
            bf16x8 bfg = ld_frag(s_b, brow, k0 * 32 + kf, 128);
            acc[n0] = __builtin_amdgcn_mfma_f32_16x16x32_bf16(af[k0], bfg, acc[n0], 0, 0, 0);
        }
    }
    // residual + LN1 -> acc = z1
    #pragma unroll
    for (int n0 = 0; n0 < 8; ++n0)
        #pragma unroll
        for (int i = 0; i < 4; ++i)
            acc[n0][i] += z[(size_t)(r0 + i) * 128 + n0 * 16 + cbase];
    {
        float s1[4] = {0,0,0,0}, s2[4] = {0,0,0,0};
        #pragma unroll
        for (int n0 = 0; n0 < 8; ++n0)
            #pragma unroll
            for (int i = 0; i < 4; ++i) { float v = acc[n0][i]; s1[i] += v; s2[i] += v * v; }
        #pragma unroll
        for (int m = 1; m < 16; m <<= 1)
            #pragma unroll
            for (int i = 0; i < 4; ++i) { s1[i] += __shfl_xor(s1[i], m); s2[i] += __shfl_xor(s2[i], m); }
        #pragma unroll
        for (int i = 0; i < 4; ++i) {
            float mu = s1[i] * (1.f / D_);
            float var = s2[i] * (1.f / D_) - mu * mu;
            float rstd = rsqrtf(var + 1e-5f);
            #pragma unroll
            for (int n0 = 0; n0 < 8; ++n0) {
                float gv = g1[n0 * 16 + cbase], bev = be1[n0 * 16 + cbase];
                acc[n0][i] = (acc[n0][i] - mu) * rstd * gv + bev;
            }
        }
    }
    // write z1 bf16 to s_a (wave-private rows; af already consumed)
    #pragma unroll
    for (int n0 = 0; n0 < 8; ++n0)
        #pragma unroll
        for (int i = 0; i < 4; ++i) {
            int row = lrow0 + i;
            s_a[row * 128 + ((n0 * 16 + cbase) ^ ((row & 7) << 3))] = (short)bf16_rne(acc[n0][i]);
        }
    bf16x8 af1[4];
    #pragma unroll
    for (int k0 = 0; k0 < 4; ++k0) af1[k0] = ld_frag(s_a, arow, k0 * 32 + kf, 128);

    // ---- ff1 (2 chunks of N=128) -> s_f
    for (int ch = 0; ch < 2; ++ch) {
        __syncthreads();
        stage_b(s_b, W1T + ch * 128 * 128, tid);
        __syncthreads();
        #pragma unroll
        for (int n0 = 0; n0 < 8; ++n0) {
            const int ncol = ch * 128 + n0 * 16 + cbase;
            const int brow = n0 * 16 + cbase;
            float bv = b1[ncol];
            f32x4 a = {bv, bv, bv, bv};
            #pragma unroll
            for (int k0 = 0; k0 < 4; ++k0) {
                bf16x8 bfg = ld_frag(s_b, brow, k0 * 32 + kf, 128);
                a = __builtin_amdgcn_mfma_f32_16x16x32_bf16(af1[k0], bfg, a, 0, 0, 0);
            }
            #pragma unroll
            for (int i = 0; i < 4; ++i) {
                int row = lrow0 + i;
                s_f[row * 256 + (ncol ^ ((row & 7) << 3))] = (short)bf16_rne(fmaxf(a[i], 0.f));
            }
        }
    }
    // ---- ff2 (K=256 in 2 slices)
    f32x4 acc2[8];
    #pragma unroll
    for (int n0 = 0; n0 < 8; ++n0) {
        float bv = b2[n0 * 16 + cbase];
        acc2[n0] = (f32x4){bv, bv, bv, bv};
    }
    for (int kc = 0; kc < 2; ++kc) {
        __syncthreads();
        #pragma unroll
        for (int it = 0; it < 8; ++it) {
            int cc = it * 256 + tid;
            int row = cc >> 4, ke = (cc & 15) * 8;
            uint4 v = *(const uint4*)&W2T[row * 256 + kc * 128 + ke];
            *(uint4*)&s_b[row * 128 + (ke ^ ((row & 7) << 3))] = v;
        }
        __syncthreads();
        bf16x8 af2[4];
        #pragma unroll
        for (int k0 = 0; k0 < 4; ++k0)
            af2[k0] = ld_frag(s_f, arow, kc * 128 + k0 * 32 + kf, 256);
        #pragma unroll
        for (int n0 = 0; n0 < 8; ++n0) {
            const int brow = n0 * 16 + cbase;
            #pragma unroll
            for (int k0 = 0; k0 < 4; ++k0) {
                bf16x8 bfg = ld_frag(s_b, brow, k0 * 32 + kf, 128);
                acc2[n0] = __builtin_amdgcn_mfma_f32_16x16x32_bf16(af2[k0], bfg, acc2[n0], 0, 0, 0);
            }
        }
    }
    // residual (z1 from regs) + LN2
    #pragma unroll
    for (int n0 = 0; n0 < 8; ++n0)
        #pragma unroll
        for (int i = 0; i < 4; ++i)
            acc2[n0][i] += acc[n0][i];
    float s1[4] = {0,0,0,0}, s2[4] = {0,0,0,0};
    #pragma unroll
    for (int n0 = 0; n0 < 8; ++n0)
        #pragma unroll
        for (int i = 0; i < 4; ++i) { float v = acc2[n0][i]; s1[i] += v; s2[i] += v * v; }
    #pragma unroll
    for (int m = 1; m < 16; m <<= 1)
        #pragma unroll
        for (int i = 0; i < 4; ++i) { s1[i] += __shfl_xor(s1[i], m); s2[i] += __shfl_xor(s2[i], m); }
    #pragma unroll
    for (int i = 0; i < 4; ++i) {
        float mu = s1[i] * (1.f / D_);
        float var = s2[i] * (1.f / D_) - mu * mu;
        float rstd = rsqrtf(var + 1e-5f);
        #pragma unroll
        for (int n0 = 0; n0 < 8; ++n0) {
            float gv = g2[n0 * 16 + cbase], bev = be2[n0 * 16 + cbase];
            z[(size_t)(r0 + i) * 128 + n0 * 16 + cbase] = (acc2[n0][i] - mu) * rstd * gv + bev;
        }
    }
}

// ---------------------------------------------------------------------------
__global__ __launch_bounds__(64) void heads_kernel(
    const float* __restrict__ z, const float* __restrict__ hw1, const float* __restrict__ hb1,
    const float* __restrict__ hw2, const float* __restrict__ hb2, float* __restrict__ out)
{
    const int k = blockIdx.x >> 8;
    const int b = blockIdx.x & 255;
    const int tid = threadIdx.x;
    __shared__ float s_last[D_];
    __shared__ float s_h1[64];
    const float* zr = z + (size_t)(b * T_ + (T_ - 1)) * D_;
    s_last[tid] = zr[tid];
    s_last[tid + 64] = zr[tid + 64];
    __syncthreads();
    float acc = hb1[k * 64 + tid];
    const float* w1 = hw1 + (size_t)k * D_ * 64;
    for (int dd = 0; dd < D_; ++dd) acc += s_last[dd] * w1[dd * 64 + tid];
    s_h1[tid] = fmaxf(acc, 0.f);
    __syncthreads();
    if (tid < 5) {
        float o = hb2[k * 5 + tid];
        const float* w2 = hw2 + (size_t)k * 64 * 5;
        for (int j = 0; j < 64; ++j) o += s_h1[j] * w2[j * 5 + tid];
        out[(size_t)k * (B_ * 5) + b * 5 + tid] = o;
    }
}

// ---------------------------------------------------------------------------
extern "C" void kernel_launch(void* const* d_in, const int* in_sizes, int n_in,
                              void* d_out, int out_size, void* d_ws, size_t ws_size,
                              hipStream_t stream) {
    const float* x      = (const float*)d_in[0];
    const int*   ei     = (const int*)  d_in[1];
    const float* gcn_w  = (const float*)d_in[2];
    const float* gcn_b  = (const float*)d_in[3];
    const float* gat_w  = (const float*)d_in[4];
    const float* a_src  = (const float*)d_in[5];
    const float* a_dst  = (const float*)d_in[6];
    const float* gat_b  = (const float*)d_in[7];
    const float* gln_g  = (const float*)d_in[8];
    const float* gln_b  = (const float*)d_in[9];
    const float* tw_qkv = (const float*)d_in[10];
    const float* tb_qkv = (const float*)d_in[11];
    const float* tw_o   = (const float*)d_in[12];
    const float* tb_o   = (const float*)d_in[13];
    const float* ln1_g  = (const float*)d_in[14];
    const float* ln1_b  = (const float*)d_in[15];
    const float* w_ff1  = (const float*)d_in[16];
    const float* b_ff1  = (const float*)d_in[17];
    const float* w_ff2  = (const float*)d_in[18];
    const float* b_ff2  = (const float*)d_in[19];
    const float* ln2_g  = (const float*)d_in[20];
    const float* ln2_b  = (const float*)d_in[21];
    const float* hw1    = (const float*)d_in[22];
    const float* hb1    = (const float*)d_in[23];
    const float* hw2    = (const float*)d_in[24];
    const float* hb2    = (const float*)d_in[25];
    float* out = (float*)d_out;
    float* ws  = (float*)d_ws;

    float* z    = ws + WS_Z;
    float* qkv  = ws + WS_QKV;
    float* obuf = ws + WS_OBUF;
    short* wbf  = (short*)(ws + WS_WBF);

    const int E = in_sizes[1] / 2;   // 20
    const int E2 = E + N_;           // 25

    setup_kernel<<<1, 64, 0, stream>>>(ei, ws, E);
    prep_kernel<<<98, 256, 0, stream>>>(tw_qkv, tw_o, w_ff1, w_ff2, gat_w, wbf);
    graph_fused<<<BT_ / 16, 256, 0, stream>>>(x, gcn_w, gcn_b, a_src, a_dst, gat_b,
                                              gln_g, gln_b, ws, wbf + WOFF_GATW, z, E2);
    for (int i = 0; i < 3; ++i) {
        qkv_mfma<<<BT_ / 64, 256, 0, stream>>>(z, wbf + WOFF_QKV(i),
                                               tb_qkv + (size_t)i * 3 * D_, qkv);
        attn_kernel<<<B_ * HH_, 256, 0, stream>>>(qkv, obuf);
        oproj_ff_mfma<<<BT_ / 64, 256, 0, stream>>>(obuf, wbf + WOFF_O(i),
                                                    tb_o + (size_t)i * D_,
                                                    ln1_g + (size_t)i * D_, ln1_b + (size_t)i * D_,
                                                    wbf + WOFF_FF1(i), b_ff1 + (size_t)i * FF_,
                                                    wbf + WOFF_FF2(i), b_ff2 + (size_t)i * D_,
                                                    ln2_g + (size_t)i * D_, ln2_b + (size_t)i * D_, z);
    }
    heads_kernel<<<6 * B_, 64, 0, stream>>>(z, hw1, hb1, hw2, hb2, out);
}

// Round 6
// 455.318 us; speedup vs baseline: 2.8832x; 1.0795x over previous
//
#include <hip/hip_runtime.h>
#include <hip/hip_bf16.h>

// Problem constants (fixed by the reference)
#define B_  256
#define T_  72
#define N_  5
#define F_  10
#define D_  128
#define HH_ 4
#define CC_ 32
#define FF_ 256
#define BT_ (B_*T_)   // 18432
#define E2MAX 32

// ---------------- ws layout (float offsets) ----------------
#define WS_Z    256
#define WS_QKV  (WS_Z + BT_*D_)
#define WS_OBUF (WS_QKV + BT_*3*D_)
#define WS_WBF  (WS_OBUF + BT_*D_)      // bf16 weight region

// bf16 weight offsets (in shorts, from WS_WBF base)
#define WOFF_QKV(i)  ((i)*49152)                 // [384][128]
#define WOFF_O(i)    (147456 + (i)*16384)        // [128][128]
#define WOFF_FF1(i)  (196608 + (i)*32768)        // [256][128]
#define WOFF_FF2(i)  (294912 + (i)*32768)        // [128][256]
#define WOFF_GATW    393216                      // [128][64]

typedef __attribute__((ext_vector_type(8))) short bf16x8;
typedef __attribute__((ext_vector_type(4))) float f32x4;

__device__ __forceinline__ unsigned short bf16_rne(float x) {
    unsigned u = __float_as_uint(x);
    unsigned r = (u + 0x7FFFu + ((u >> 16) & 1u)) >> 16;
    return (unsigned short)r;
}
__device__ __forceinline__ unsigned bf16pk(float a, float b) {
    return (unsigned)bf16_rne(a) | ((unsigned)bf16_rne(b) << 16);
}
__device__ __forceinline__ float bf2f(short s) {
    return __uint_as_float(((unsigned)(unsigned short)s) << 16);
}

// ---------------------------------------------------------------------------
__global__ void setup_kernel(const int* __restrict__ ei, float* __restrict__ ws, int E) {
    if (threadIdx.x != 0 || blockIdx.x != 0) return;
    int* wsi = (int*)ws;
    const int N = N_;
    int E2 = E + N;
    int src2[E2MAX], dst2[E2MAX];
    for (int e = 0; e < E; ++e) { src2[e] = ei[e]; dst2[e] = ei[E + e]; }
    for (int n = 0; n < N; ++n) { src2[E + n] = n; dst2[E + n] = n; }
    float A[N_ * N_];
    for (int i = 0; i < N * N; ++i) A[i] = 0.f;
    for (int e = 0; e < E2; ++e) A[dst2[e] * N + src2[e]] += 1.f;
    float dinv[N_];
    for (int n = 0; n < N; ++n) {
        float s = 0.f;
        for (int j = 0; j < N; ++j) s += A[n * N + j];
        dinv[n] = (s > 0.f) ? rsqrtf(s) : 0.f;
    }
    for (int n = 0; n < N; ++n)
        for (int j = 0; j < N; ++j)
            ws[n * N + j] = dinv[n] * A[n * N + j] * dinv[j];
    int cnt[N_];
    for (int n = 0; n < N; ++n) cnt[n] = 0;
    for (int e = 0; e < E2; ++e) cnt[dst2[e]]++;
    int off = 0;
    for (int n = 0; n < N; ++n) { wsi[96 + n] = off; off += cnt[n]; }
    wsi[96 + N] = off;
    int cur[N_];
    for (int n = 0; n < N; ++n) cur[n] = wsi[96 + n];
    for (int e = 0; e < E2; ++e) wsi[104 + cur[dst2[e]]++] = e;
    for (int e = 0; e < E2; ++e) { wsi[32 + e] = src2[e]; wsi[64 + e] = dst2[e]; }
}

// ---------------------------------------------------------------------------
// Weight prep: transpose R x C fp32 -> [C][R] bf16 into ws.
// blocks 0..95: transformer weights; 96..97: gat_w [64][128] -> [128][64]
__global__ __launch_bounds__(256) void prep_kernel(
    const float* __restrict__ tw_qkv, const float* __restrict__ tw_o,
    const float* __restrict__ w_ff1, const float* __restrict__ w_ff2,
    const float* __restrict__ gat_w, short* __restrict__ wbf)
{
    __shared__ float s_t[64][65];
    const int tid = threadIdx.x;
    int t = blockIdx.x;
    const float* src; short* dst; int R, C, tr, tc;
    if (t >= 96) { int q = t - 96; src = gat_w; dst = wbf + WOFF_GATW; R = 64; C = 128; tr = 0; tc = q; }
    else {
        int layer = t / 32, r32 = t % 32;
        if (r32 < 12)      { src = tw_qkv + layer * (128*384); dst = wbf + WOFF_QKV(layer); R = 128; C = 384; tr = r32 / 6;  tc = r32 % 6; }
        else if (r32 < 16) { int q = r32 - 12; src = tw_o + layer * 16384; dst = wbf + WOFF_O(layer);  R = 128; C = 128; tr = q >> 1; tc = q & 1; }
        else if (r32 < 24) { int q = r32 - 16; src = w_ff1 + layer * 32768; dst = wbf + WOFF_FF1(layer); R = 128; C = 256; tr = q >> 2; tc = q & 3; }
        else               { int q = r32 - 24; src = w_ff2 + layer * 32768; dst = wbf + WOFF_FF2(layer); R = 256; C = 128; tr = q >> 1; tc = q & 1; }
    }
    #pragma unroll
    for (int it = 0; it < 16; ++it) {
        int e = it * 256 + tid;
        int r = e >> 6, c = e & 63;
        s_t[r][c] = src[(size_t)(tr*64 + r) * C + tc*64 + c];
    }
    __syncthreads();
    #pragma unroll
    for (int it = 0; it < 16; ++it) {
        int e = it * 256 + tid;
        int c = e >> 6, r = e & 63;
        dst[(size_t)(tc*64 + c) * R + tr*64 + r] = (short)bf16_rne(s_t[r][c]);
    }
}

// ---------------------------------------------------------------------------
// MFMA helpers: A stored [rows][K] bf16 LDS, swizzle kelem ^ ((row&7)<<3).
__device__ __forceinline__ bf16x8 ld_frag(const short* s, int row, int kbase, int ldk) {
    return *(const bf16x8*)&s[row * ldk + (kbase ^ ((row & 7) << 3))];
}
// stage 64x128 fp32 -> bf16 swizzled LDS
__device__ __forceinline__ void stage_a(short* s_a, const float* __restrict__ src, int tid) {
    const float2* s2 = (const float2*)src;
    #pragma unroll
    for (int it = 0; it < 16; ++it) {
        int i2 = it * 256 + tid;
        int row = i2 >> 6, ke = (i2 & 63) * 2;
        float2 v = s2[i2];
        *(unsigned*)&s_a[row * 128 + (ke ^ ((row & 7) << 3))] = bf16pk(v.x, v.y);
    }
}
// stage 128 rows x 128 k of contiguous bf16 [N][128] -> swizzled LDS
__device__ __forceinline__ void stage_b(short* s_b, const short* __restrict__ src, int tid) {
    const uint4* s4 = (const uint4*)src;
    #pragma unroll
    for (int it = 0; it < 8; ++it) {
        int c = it * 256 + tid;
        int row = c >> 4, ke = (c & 15) * 8;
        *(uint4*)&s_b[row * 128 + (ke ^ ((row & 7) << 3))] = s4[c];
    }
}

// ---------------------------------------------------------------------------
// G1: x -> GCN(tanh) -> h = gcn @ gat_w (MFMA) -> h (bf16 global), a_s/a_d (global)
// block = 16 tokens (80 rows), 256 threads, LDS ~13.5 KB
__global__ __launch_bounds__(256) void gcn_h_mfma(
    const float* __restrict__ x, const float* __restrict__ gcn_w, const float* __restrict__ gcn_b,
    const float* __restrict__ a_src, const float* __restrict__ a_dst,
    const float* __restrict__ ws, const short* __restrict__ gwT,
    short* __restrict__ hbuf, float* __restrict__ asb, float* __restrict__ adb)
{
    __shared__ float s_x[16 * 50];
    __shared__ float s_an[25];
    __shared__ short s_gcn[80 * 64];     // bf16, swizzled

    const int tid = threadIdx.x;
    const int tok0 = blockIdx.x * 16;

    for (int i = tid; i < 16 * 50; i += 256) s_x[i] = x[(size_t)tok0 * 50 + i];
    if (tid < 25) s_an[tid] = ws[tid];
    __syncthreads();

    // ---- GCN: 512 (token, k-pair) items over 2 iterations
    #pragma unroll
    for (int it = 0; it < 2; ++it) {
        int idx = it * 256 + tid;
        int tl = idx >> 5, kp = idx & 31;
        int k0 = kp * 2;
        float w0[F_], w1[F_];
        #pragma unroll
        for (int f = 0; f < F_; ++f) { w0[f] = gcn_w[f * 64 + k0]; w1[f] = gcn_w[f * 64 + k0 + 1]; }
        float b0 = gcn_b[k0], b1 = gcn_b[k0 + 1];
        float xw0[N_], xw1[N_];
        #pragma unroll
        for (int n = 0; n < N_; ++n) {
            float a0 = b0, a1 = b1;
            #pragma unroll
            for (int f = 0; f < F_; ++f) {
                float xv = s_x[tl * 50 + n * 10 + f];
                a0 += xv * w0[f]; a1 += xv * w1[f];
            }
            xw0[n] = a0; xw1[n] = a1;
        }
        #pragma unroll
        for (int n = 0; n < N_; ++n) {
            float s0 = 0.f, s1 = 0.f;
            #pragma unroll
            for (int j = 0; j < N_; ++j) { float an = s_an[n * 5 + j]; s0 += an * xw0[j]; s1 += an * xw1[j]; }
            float e0 = __expf(2.f * fabsf(s0)), e1 = __expf(2.f * fabsf(s1));
            float t0 = copysignf(1.f - 2.f / (e0 + 1.f), s0);
            float t1 = copysignf(1.f - 2.f / (e1 + 1.f), s1);
            int row = tl * 5 + n;
            *(unsigned*)&s_gcn[row * 64 + (k0 ^ ((row & 7) << 3))] = bf16pk(t0, t1);
        }
    }
    __syncthreads();

    // ---- h = gcn @ gat_w via MFMA; wave w owns head w (cols 32w..32w+31)
    const int w = tid >> 6, lane = tid & 63;
    const int c = lane & 15, g = lane >> 4;
    const int kf = g * 8;
    bf16x8 bfr[2][2];
    #pragma unroll
    for (int nn = 0; nn < 2; ++nn)
        #pragma unroll
        for (int k0 = 0; k0 < 2; ++k0)
            bfr[nn][k0] = *(const bf16x8*)&gwT[(w * 32 + nn * 16 + c) * 64 + k0 * 32 + kf];
    const float as0 = a_src[w * 32 + c],      as1 = a_src[w * 32 + 16 + c];
    const float ad0 = a_dst[w * 32 + c],      ad1 = a_dst[w * 32 + 16 + c];
    #pragma unroll
    for (int m = 0; m < 5; ++m) {
        bf16x8 af0 = ld_frag(s_gcn, m * 16 + c, kf, 64);
        bf16x8 af1 = ld_frag(s_gcn, m * 16 + c, 32 + kf, 64);
        f32x4 a0 = {0,0,0,0}, a1 = {0,0,0,0};
        a0 = __builtin_amdgcn_mfma_f32_16x16x32_bf16(af0, bfr[0][0], a0, 0, 0, 0);
        a0 = __builtin_amdgcn_mfma_f32_16x16x32_bf16(af1, bfr[0][1], a0, 0, 0, 0);
        a1 = __builtin_amdgcn_mfma_f32_16x16x32_bf16(af0, bfr[1][0], a1, 0, 0, 0);
        a1 = __builtin_amdgcn_mfma_f32_16x16x32_bf16(af1, bfr[1][1], a1, 0, 0, 0);
        float ps[4], pd[4];
        #pragma unroll
        for (int i = 0; i < 4; ++i) {
            int row = m * 16 + g * 4 + i;
            size_t gr = (size_t)(tok0 * 5 + row) * 128;
            hbuf[gr + w * 32 + c]      = (short)bf16_rne(a0[i]);
            hbuf[gr + w * 32 + 16 + c] = (short)bf16_rne(a1[i]);
            ps[i] = a0[i] * as0 + a1[i] * as1;
            pd[i] = a0[i] * ad0 + a1[i] * ad1;
        }
        #pragma unroll
        for (int mm = 1; mm < 16; mm <<= 1)
            #pragma unroll
            for (int i = 0; i < 4; ++i) { ps[i] += __shfl_xor(ps[i], mm); pd[i] += __shfl_xor(pd[i], mm); }
        if (c == 0) {
            #pragma unroll
            for (int i = 0; i < 4; ++i) {
                int row = m * 16 + g * 4 + i;
                asb[(size_t)(tok0 * 5 + row) * 4 + w] = ps[i];
                adb[(size_t)(tok0 * 5 + row) * 4 + w] = pd[i];
            }
        }
    }
}

// ---------------------------------------------------------------------------
// G2: alpha softmax + aggregate + gat_b + LN + mean + PE -> z
// wave-per-token: block = 4 tokens, 256 threads, tiny LDS, 4608 blocks
__global__ __launch_bounds__(256) void gat_agg(
    const short* __restrict__ hbuf, const float* __restrict__ asb, const float* __restrict__ adb,
    const float* __restrict__ gat_b, const float* __restrict__ gln_g, const float* __restrict__ gln_b,
    const float* __restrict__ ws, float* __restrict__ z, int E2)
{
    __shared__ int   s_src[E2MAX], s_csr_off[N_ + 1], s_csr_e[E2MAX];
    __shared__ float s_alpha[4][E2MAX][4];
    __shared__ short s_h[4 * 5 * 128];

    const int tid = threadIdx.x;
    const int wv = tid >> 6, lane = tid & 63;
    const int tok = blockIdx.x * 4 + wv;
    const int* wsi = (const int*)ws;

    if (tid < E2) { s_src[tid] = wsi[32 + tid]; s_csr_e[tid] = wsi[104 + tid]; }
    if (tid < N_ + 1) s_csr_off[tid] = wsi[96 + tid];
    {   // stage the block's 4x5 h rows (contiguous 2560 shorts = 320 uint4)
        const uint4* hb4 = (const uint4*)(hbuf + (size_t)blockIdx.x * 4 * 5 * 128);
        uint4* sh4 = (uint4*)s_h;
        #pragma unroll
        for (int it = 0; it < 2; ++it) {
            int i = it * 256 + tid;
            if (i < 320) sh4[i] = hb4[i];
        }
    }
    __syncthreads();

    // ---- alpha: lanes 0..19 per wave, one (dst, head) each, 3 passes
    if (lane < 20) {
        int dn = lane >> 2, head = lane & 3;
        int j0 = s_csr_off[dn], j1 = s_csr_off[dn + 1];
        float adv = adb[(size_t)(tok * 5 + dn) * 4 + head];
        float mx = -1e30f;
        for (int j = j0; j < j1; ++j) {
            int e = s_csr_e[j];
            float ev = asb[(size_t)(tok * 5 + s_src[e]) * 4 + head] + adv;
            ev = ev > 0.f ? ev : 0.2f * ev;
            mx = fmaxf(mx, ev);
        }
        float den = 0.f;
        for (int j = j0; j < j1; ++j) {
            int e = s_csr_e[j];
            float ev = asb[(size_t)(tok * 5 + s_src[e]) * 4 + head] + adv;
            ev = ev > 0.f ? ev : 0.2f * ev;
            float ex = __expf(ev - mx);
            den += ex;
            s_alpha[wv][e][head] = ex;
        }
        float r = 1.f / den;
        for (int j = j0; j < j1; ++j) s_alpha[wv][s_csr_e[j]][head] *= r;
    }
    __syncthreads();

    // ---- aggregate + gat_b + per-node LN + mean + PE
    const int h0 = lane >> 5, h1 = 2 + (lane >> 5);
    const float gb0 = gat_b[lane],      gb1 = gat_b[lane + 64];
    const float gg0 = gln_g[lane],      gg1 = gln_g[lane + 64];
    const float gB0 = gln_b[lane],      gB1 = gln_b[lane + 64];
    float v0[N_], v1[N_];
    #pragma unroll
    for (int n = 0; n < N_; ++n) {
        float a0 = 0.f, a1 = 0.f;
        int j0 = s_csr_off[n], j1 = s_csr_off[n + 1];
        for (int j = j0; j < j1; ++j) {
            int e = s_csr_e[j];
            int rb = (wv * 5 + s_src[e]) * 128;
            a0 += s_alpha[wv][e][h0] * bf2f(s_h[rb + lane]);
            a1 += s_alpha[wv][e][h1] * bf2f(s_h[rb + lane + 64]);
        }
        v0[n] = a0 + gb0; v1[n] = a1 + gb1;
    }
    float r1[N_], r2[N_];
    #pragma unroll
    for (int n = 0; n < N_; ++n) { r1[n] = v0[n] + v1[n]; r2[n] = v0[n]*v0[n] + v1[n]*v1[n]; }
    #pragma unroll
    for (int mm = 1; mm < 64; mm <<= 1)
        #pragma unroll
        for (int n = 0; n < N_; ++n) { r1[n] += __shfl_xor(r1[n], mm); r2[n] += __shfl_xor(r2[n], mm); }
    float z0 = 0.f, z1 = 0.f;
    #pragma unroll
    for (int n = 0; n < N_; ++n) {
        float mu = r1[n] * (1.f / D_);
        float var = r2[n] * (1.f / D_) - mu * mu;
        float rstd = rsqrtf(var + 1e-5f);
        z0 += (v0[n] - mu) * rstd * gg0 + gB0;
        z1 += (v1[n] - mu) * rstd * gg1 + gB1;
    }
    z0 *= (1.f / N_); z1 *= (1.f / N_);
    const float cpe = -9.210340371976184f / (float)D_;
    int t = tok % T_;
    float dv0 = __expf((float)(lane & ~1) * cpe);
    float dv1 = __expf((float)((lane + 64) & ~1) * cpe);
    float ang0 = (float)t * dv0, ang1 = (float)t * dv1;
    z0 += (lane & 1) ? __cosf(ang0) : __sinf(ang0);
    z1 += (lane & 1) ? __cosf(ang1) : __sinf(ang1);
    z[(size_t)tok * D_ + lane] = z0;
    z[(size_t)tok * D_ + 64 + lane] = z1;
}

// ---------------------------------------------------------------------------
// qkv = z @ Wqkv + b : M-tile 64, 4 waves, 3 N-chunks of 128
__global__ __launch_bounds__(256) void qkv_mfma(
    const float* __restrict__ z, const short* __restrict__ WT, const float* __restrict__ bias,
    float* __restrict__ qkv)
{
    __shared__ short s_a[64 * 128];
    __shared__ short s_b[128 * 128];
    const int tid = threadIdx.x;
    const int w = tid >> 6, lane = tid & 63;
    const int tok0 = blockIdx.x * 64;
    stage_a(s_a, z + (size_t)tok0 * 128, tid);
    __syncthreads();
    bf16x8 af[4];
    const int arow = w * 16 + (lane & 15);
    const int kf = (lane >> 4) * 8;
    #pragma unroll
    for (int k0 = 0; k0 < 4; ++k0) af[k0] = ld_frag(s_a, arow, k0 * 32 + kf, 128);

    for (int ch = 0; ch < 3; ++ch) {
        __syncthreads();
        stage_b(s_b, WT + ch * 128 * 128, tid);
        __syncthreads();
        #pragma unroll
        for (int n0 = 0; n0 < 8; ++n0) {
            const int ncol = ch * 128 + n0 * 16 + (lane & 15);
            const int brow = n0 * 16 + (lane & 15);
            float bv = bias[ncol];
            f32x4 acc = {bv, bv, bv, bv};
            #pragma unroll
            for (int k0 = 0; k0 < 4; ++k0) {
                bf16x8 bfg = ld_frag(s_b, brow, k0 * 32 + kf, 128);
                acc = __builtin_amdgcn_mfma_f32_16x16x32_bf16(af[k0], bfg, acc, 0, 0, 0);
            }
            const int r0 = tok0 + w * 16 + (lane >> 4) * 4;
            #pragma unroll
            for (int i = 0; i < 4; ++i)
                qkv[(size_t)(r0 + i) * 384 + ncol] = acc[i];
        }
    }
}

// ---------------------------------------------------------------------------
// full attention for one (batch, head): scores + softmax + PV, all in LDS (fp32)
__global__ __launch_bounds__(256) void attn_kernel(
    const float* __restrict__ qkv, float* __restrict__ obuf)
{
    const int bh = blockIdx.x;
    const int b = bh >> 2, h = bh & 3;
    __shared__ float s_q[T_][33], s_k[T_][33], s_v[T_][33];
    __shared__ float s_p[T_][73];
    const int tid = threadIdx.x;
    const float* base = qkv + (size_t)b * T_ * 384 + h * 32;
    for (int idx = tid; idx < T_ * 32; idx += 256) {
        int i = idx >> 5, c = idx & 31;
        s_q[i][c] = base[i * 384 + c];
        s_k[i][c] = base[i * 384 + 128 + c];
        s_v[i][c] = base[i * 384 + 256 + c];
    }
    __syncthreads();
    const float scale = 0.17677669529663687f;
    for (int idx = tid; idx < T_ * T_; idx += 256) {
        int i = idx / T_, j = idx - i * T_;
        float s = 0.f;
        #pragma unroll
        for (int c = 0; c < 32; ++c) s += s_q[i][c] * s_k[j][c];
        s_p[i][j] = s * scale;
    }
    __syncthreads();
    if (tid < T_) {
        float mx = -1e30f;
        for (int j = 0; j < T_; ++j) mx = fmaxf(mx, s_p[tid][j]);
        float den = 0.f;
        for (int j = 0; j < T_; ++j) { float e = __expf(s_p[tid][j] - mx); s_p[tid][j] = e; den += e; }
        float r = 1.f / den;
        for (int j = 0; j < T_; ++j) s_p[tid][j] *= r;
    }
    __syncthreads();
    for (int idx = tid; idx < T_ * 32; idx += 256) {
        int i = idx >> 5, c = idx & 31;
        float o = 0.f;
        for (int j = 0; j < T_; ++j) o += s_p[i][j] * s_v[j][c];
        obuf[(size_t)(b * T_ + i) * D_ + h * 32 + c] = o;
    }
}

// ---------------------------------------------------------------------------
// Fused: z1 = LN1(z + obuf@Wo + bo); z = LN2(z1 + relu(z1@W1+b1)@W2 + b2)
__global__ __launch_bounds__(256) void oproj_ff_mfma(
    const float* __restrict__ obuf, const short* __restrict__ WoT, const float* __restrict__ bo,
    const float* __restrict__ g1, const float* __restrict__ be1,
    const short* __restrict__ W1T, const float* __restrict__ b1,
    const short* __restrict__ W2T, const float* __restrict__ b2,
    const float* __restrict__ g2, const float* __restrict__ be2,
    float* __restrict__ z)
{
    __shared__ short s_a[64 * 128];
    __shared__ short s_b[128 * 128];
    __shared__ short s_f[64 * 256];
    const int tid = threadIdx.x;
    const int w = tid >> 6, lane = tid & 63;
    const int tok0 = blockIdx.x * 64;
    const int cbase = lane & 15;
    const int arow = w * 16 + cbase;
    const int kf = (lane >> 4) * 8;
    const int r0 = tok0 + w * 16 + (lane >> 4) * 4;
    const int lrow0 = w * 16 + (lane >> 4) * 4;

    stage_a(s_a, obuf + (size_t)tok0 * 128, tid);
    stage_b(s_b, WoT, tid);
    __syncthreads();
    bf16x8 af[4];
    #pragma unroll
    for (int k0 = 0; k0 < 4; ++k0) af[k0] = ld_frag(s_a, arow, k0 * 32 + kf, 128);

    // ---- o-proj
    f32x4 acc[8];
    #pragma unroll
    for (int n0 = 0; n0 < 8; ++n0) {
        float bv = bo[n0 * 16 + cbase];
        acc[n0] = (f32x4){bv, bv, bv, bv};
        const int brow = n0 * 16 + cbase;
        #pragma unroll
        for (int k0 = 0; k0 < 4; ++k0) {
            bf16x8 bfg = ld_frag(s_b, brow, k0 * 32 + kf, 128);
            acc[n0] = __builtin_amdgcn_mfma_f32_16x16x32_bf16(af[k0], bfg, acc[n0], 0, 0, 0);
        }
    }
    // residual + LN1 -> acc = z1
    #pragma unroll
    for (int n0 = 0; n0 < 8; ++n0)
        #pragma unroll
        for (int i = 0; i < 4; ++i)
            acc[n0][i] += z[(size_t)(r0 + i) * 128 + n0 * 16 + cbase];
    {
        float s1[4] = {0,0,0,0}, s2[4] = {0,0,0,0};
        #pragma unroll
        for (int n0 = 0; n0 < 8; ++n0)
            #pragma unroll
            for (int i = 0; i < 4; ++i) { float v = acc[n0][i]; s1[i] += v; s2[i] += v * v; }
        #pragma unroll
        for (int m = 1; m < 16; m <<= 1)
            #pragma unroll
            for (int i = 0; i < 4; ++i) { s1[i] += __shfl_xor(s1[i], m); s2[i] += __shfl_xor(s2[i], m); }
        #pragma unroll
        for (int i = 0; i < 4; ++i) {
            float mu = s1[i] * (1.f / D_);
            float var = s2[i] * (1.f / D_) - mu * mu;
            float rstd = rsqrtf(var + 1e-5f);
            #pragma unroll
            for (int n0 = 0; n0 < 8; ++n0) {
                float gv = g1[n0 * 16 + cbase], bev = be1[n0 * 16 + cbase];
                acc[n0][i] = (acc[n0][i] - mu) * rstd * gv + bev;
            }
        }
    }
    // write z1 bf16 to s_a (wave-private rows; af already consumed)
    #pragma unroll
    for (int n0 = 0; n0 < 8; ++n0)
        #pragma unroll
        for (int i = 0; i < 4; ++i) {
            int row = lrow0 + i;
            s_a[row * 128 + ((n0 * 16 + cbase) ^ ((row & 7) << 3))] = (short)bf16_rne(acc[n0][i]);
        }
    bf16x8 af1[4];
    #pragma unroll
    for (int k0 = 0; k0 < 4; ++k0) af1[k0] = ld_frag(s_a, arow, k0 * 32 + kf, 128);

    // ---- ff1 (2 chunks of N=128) -> s_f
    for (int ch = 0; ch < 2; ++ch) {
        __syncthreads();
        stage_b(s_b, W1T + ch * 128 * 128, tid);
        __syncthreads();
        #pragma unroll
        for (int n0 = 0; n0 < 8; ++n0) {
            const int ncol = ch * 128 + n0 * 16 + cbase;
            const int brow = n0 * 16 + cbase;
            float bv = b1[ncol];
            f32x4 a = {bv, bv, bv, bv};
            #pragma unroll
            for (int k0 = 0; k0 < 4; ++k0) {
                bf16x8 bfg = ld_frag(s_b, brow, k0 * 32 + kf, 128);
                a = __builtin_amdgcn_mfma_f32_16x16x32_bf16(af1[k0], bfg, a, 0, 0, 0);
            }
            #pragma unroll
            for (int i = 0; i < 4; ++i) {
                int row = lrow0 + i;
                s_f[row * 256 + (ncol ^ ((row & 7) << 3))] = (short)bf16_rne(fmaxf(a[i], 0.f));
            }
        }
    }
    // ---- ff2 (K=256 in 2 slices)
    f32x4 acc2[8];
    #pragma unroll
    for (int n0 = 0; n0 < 8; ++n0) {
        float bv = b2[n0 * 16 + cbase];
        acc2[n0] = (f32x4){bv, bv, bv, bv};
    }
    for (int kc = 0; kc < 2; ++kc) {
        __syncthreads();
        #pragma unroll
        for (int it = 0; it < 8; ++it) {
            int cc = it * 256 + tid;
            int row = cc >> 4, ke = (cc & 15) * 8;
            uint4 v = *(const uint4*)&W2T[row * 256 + kc * 128 + ke];
            *(uint4*)&s_b[row * 128 + (ke ^ ((row & 7) << 3))] = v;
        }
        __syncthreads();
        bf16x8 af2[4];
        #pragma unroll
        for (int k0 = 0; k0 < 4; ++k0)
            af2[k0] = ld_frag(s_f, arow, kc * 128 + k0 * 32 + kf, 256);
        #pragma unroll
        for (int n0 = 0; n0 < 8; ++n0) {
            const int brow = n0 * 16 + cbase;
            #pragma unroll
            for (int k0 = 0; k0 < 4; ++k0) {
                bf16x8 bfg = ld_frag(s_b, brow, k0 * 32 + kf, 128);
                acc2[n0] = __builtin_amdgcn_mfma_f32_16x16x32_bf16(af2[k0], bfg, acc2[n0], 0, 0, 0);
            }
        }
    }
    // residual (z1 from regs) + LN2
    #pragma unroll
    for (int n0 = 0; n0 < 8; ++n0)
        #pragma unroll
        for (int i = 0; i < 4; ++i)
            acc2[n0][i] += acc[n0][i];
    float s1[4] = {0,0,0,0}, s2[4] = {0,0,0,0};
    #pragma unroll
    for (int n0 = 0; n0 < 8; ++n0)
        #pragma unroll
        for (int i = 0; i < 4; ++i) { float v = acc2[n0][i]; s1[i] += v; s2[i] += v * v; }
    #pragma unroll
    for (int m = 1; m < 16; m <<= 1)
        #pragma unroll
        for (int i = 0; i < 4; ++i) { s1[i] += __shfl_xor(s1[i], m); s2[i] += __shfl_xor(s2[i], m); }
    #pragma unroll
    for (int i = 0; i < 4; ++i) {
        float mu = s1[i] * (1.f / D_);
        float var = s2[i] * (1.f / D_) - mu * mu;
        float rstd = rsqrtf(var + 1e-5f);
        #pragma unroll
        for (int n0 = 0; n0 < 8; ++n0) {
            float gv = g2[n0 * 16 + cbase], bev = be2[n0 * 16 + cbase];
            z[(size_t)(r0 + i) * 128 + n0 * 16 + cbase] = (acc2[n0][i] - mu) * rstd * gv + bev;
        }
    }
}

// ---------------------------------------------------------------------------
__global__ __launch_bounds__(64) void heads_kernel(
    const float* __restrict__ z, const float* __restrict__ hw1, const float* __restrict__ hb1,
    const float* __restrict__ hw2, const float* __restrict__ hb2, float* __restrict__ out)
{
    const int k = blockIdx.x >> 8;
    const int b = blockIdx.x & 255;
    const int tid = threadIdx.x;
    __shared__ float s_last[D_];
    __shared__ float s_h1[64];
    const float* zr = z + (size_t)(b * T_ + (T_ - 1)) * D_;
    s_last[tid] = zr[tid];
    s_last[tid + 64] = zr[tid + 64];
    __syncthreads();
    float acc = hb1[k * 64 + tid];
    const float* w1 = hw1 + (size_t)k * D_ * 64;
    for (int dd = 0; dd < D_; ++dd) acc += s_last[dd] * w1[dd * 64 + tid];
    s_h1[tid] = fmaxf(acc, 0.f);
    __syncthreads();
    if (tid < 5) {
        float o = hb2[k * 5 + tid];
        const float* w2 = hw2 + (size_t)k * 64 * 5;
        for (int j = 0; j < 64; ++j) o += s_h1[j] * w2[j * 5 + tid];
        out[(size_t)k * (B_ * 5) + b * 5 + tid] = o;
    }
}

// ---------------------------------------------------------------------------
extern "C" void kernel_launch(void* const* d_in, const int* in_sizes, int n_in,
                              void* d_out, int out_size, void* d_ws, size_t ws_size,
                              hipStream_t stream) {
    const float* x      = (const float*)d_in[0];
    const int*   ei     = (const int*)  d_in[1];
    const float* gcn_w  = (const float*)d_in[2];
    const float* gcn_b  = (const float*)d_in[3];
    const float* gat_w  = (const float*)d_in[4];
    const float* a_src  = (const float*)d_in[5];
    const float* a_dst  = (const float*)d_in[6];
    const float* gat_b  = (const float*)d_in[7];
    const float* gln_g  = (const float*)d_in[8];
    const float* gln_b  = (const float*)d_in[9];
    const float* tw_qkv = (const float*)d_in[10];
    const float* tb_qkv = (const float*)d_in[11];
    const float* tw_o   = (const float*)d_in[12];
    const float* tb_o   = (const float*)d_in[13];
    const float* ln1_g  = (const float*)d_in[14];
    const float* ln1_b  = (const float*)d_in[15];
    const float* w_ff1  = (const float*)d_in[16];
    const float* b_ff1  = (const float*)d_in[17];
    const float* w_ff2  = (const float*)d_in[18];
    const float* b_ff2  = (const float*)d_in[19];
    const float* ln2_g  = (const float*)d_in[20];
    const float* ln2_b  = (const float*)d_in[21];
    const float* hw1    = (const float*)d_in[22];
    const float* hb1    = (const float*)d_in[23];
    const float* hw2    = (const float*)d_in[24];
    const float* hb2    = (const float*)d_in[25];
    float* out = (float*)d_out;
    float* ws  = (float*)d_ws;

    float* z    = ws + WS_Z;
    float* qkv  = ws + WS_QKV;
    float* obuf = ws + WS_OBUF;
    short* wbf  = (short*)(ws + WS_WBF);

    // graph-stage scratch (regions dead until layer 0 starts):
    short* hbuf = (short*)(ws + WS_QKV);       // BT*5*128 bf16 = 23.6 MB <= qkv region
    float* asb  = ws + WS_OBUF;                // BT*5*4 floats
    float* adb  = ws + WS_OBUF + BT_ * 5 * 4;  // BT*5*4 floats

    const int E = in_sizes[1] / 2;   // 20
    const int E2 = E + N_;           // 25

    setup_kernel<<<1, 64, 0, stream>>>(ei, ws, E);
    prep_kernel<<<98, 256, 0, stream>>>(tw_qkv, tw_o, w_ff1, w_ff2, gat_w, wbf);
    gcn_h_mfma<<<BT_ / 16, 256, 0, stream>>>(x, gcn_w, gcn_b, a_src, a_dst, ws,
                                             wbf + WOFF_GATW, hbuf, asb, adb);
    gat_agg<<<BT_ / 4, 256, 0, stream>>>(hbuf, asb, adb, gat_b, gln_g, gln_b, ws, z, E2);
    for (int i = 0; i < 3; ++i) {
        qkv_mfma<<<BT_ / 64, 256, 0, stream>>>(z, wbf + WOFF_QKV(i),
                                               tb_qkv + (size_t)i * 3 * D_, qkv);
        attn_kernel<<<B_ * HH_, 256, 0, stream>>>(qkv, obuf);
        oproj_ff_mfma<<<BT_ / 64, 256, 0, stream>>>(obuf, wbf + WOFF_O(i),
                                                    tb_o + (size_t)i * D_,
                                                    ln1_g + (size_t)i * D_, ln1_b + (size_t)i * D_,
                                                    wbf + WOFF_FF1(i), b_ff1 + (size_t)i * FF_,
                                                    wbf + WOFF_FF2(i), b_ff2 + (size_t)i * D_,
                                                    ln2_g + (size_t)i * D_, ln2_b + (size_t)i * D_, z);
    }
    heads_kernel<<<6 * B_, 64, 0, stream>>>(z, hw1, hb1, hw2, hb2, out);
}

// Round 7
// 342.641 us; speedup vs baseline: 3.8314x; 1.3288x over previous
//
#include <hip/hip_runtime.h>
#include <hip/hip_bf16.h>

// Problem constants (fixed by the reference)
#define B_  256
#define T_  72
#define N_  5
#define F_  10
#define D_  128
#define HH_ 4
#define CC_ 32
#define FF_ 256
#define BT_ (B_*T_)   // 18432
#define E2MAX 32

// ---------------- ws layout (float offsets) ----------------
#define WS_Z    256
#define WS_QKV  (WS_Z + BT_*D_)
#define WS_OBUF (WS_QKV + BT_*3*D_)
#define WS_WBF  (WS_OBUF + BT_*D_)      // bf16 weight region

// bf16 weight offsets (in shorts, from WS_WBF base)
#define WOFF_QKV(i)  ((i)*49152)                 // [384][128]
#define WOFF_O(i)    (147456 + (i)*16384)        // [128][128]
#define WOFF_FF1(i)  (196608 + (i)*32768)        // [256][128]
#define WOFF_FF2(i)  (294912 + (i)*32768)        // [128][256]
#define WOFF_GATW    393216                      // [128][64]

typedef __attribute__((ext_vector_type(8))) short bf16x8;
typedef __attribute__((ext_vector_type(4))) float f32x4;

__device__ __forceinline__ unsigned short bf16_rne(float x) {
    unsigned u = __float_as_uint(x);
    unsigned r = (u + 0x7FFFu + ((u >> 16) & 1u)) >> 16;
    return (unsigned short)r;
}
__device__ __forceinline__ unsigned bf16pk(float a, float b) {
    return (unsigned)bf16_rne(a) | ((unsigned)bf16_rne(b) << 16);
}
__device__ __forceinline__ float bf2f(short s) {
    return __uint_as_float(((unsigned)(unsigned short)s) << 16);
}

// ---------------------------------------------------------------------------
__global__ void setup_kernel(const int* __restrict__ ei, float* __restrict__ ws, int E) {
    if (threadIdx.x != 0 || blockIdx.x != 0) return;
    int* wsi = (int*)ws;
    const int N = N_;
    int E2 = E + N;
    int src2[E2MAX], dst2[E2MAX];
    for (int e = 0; e < E; ++e) { src2[e] = ei[e]; dst2[e] = ei[E + e]; }
    for (int n = 0; n < N; ++n) { src2[E + n] = n; dst2[E + n] = n; }
    float A[N_ * N_];
    for (int i = 0; i < N * N; ++i) A[i] = 0.f;
    for (int e = 0; e < E2; ++e) A[dst2[e] * N + src2[e]] += 1.f;
    float dinv[N_];
    for (int n = 0; n < N; ++n) {
        float s = 0.f;
        for (int j = 0; j < N; ++j) s += A[n * N + j];
        dinv[n] = (s > 0.f) ? rsqrtf(s) : 0.f;
    }
    for (int n = 0; n < N; ++n)
        for (int j = 0; j < N; ++j)
            ws[n * N + j] = dinv[n] * A[n * N + j] * dinv[j];
    int cnt[N_];
    for (int n = 0; n < N; ++n) cnt[n] = 0;
    for (int e = 0; e < E2; ++e) cnt[dst2[e]]++;
    int off = 0;
    for (int n = 0; n < N; ++n) { wsi[96 + n] = off; off += cnt[n]; }
    wsi[96 + N] = off;
    int cur[N_];
    for (int n = 0; n < N; ++n) cur[n] = wsi[96 + n];
    for (int e = 0; e < E2; ++e) wsi[104 + cur[dst2[e]]++] = e;
    for (int e = 0; e < E2; ++e) { wsi[32 + e] = src2[e]; wsi[64 + e] = dst2[e]; }
}

// ---------------------------------------------------------------------------
// Weight prep: transpose R x C fp32 -> [C][R] bf16 into ws.
__global__ __launch_bounds__(256) void prep_kernel(
    const float* __restrict__ tw_qkv, const float* __restrict__ tw_o,
    const float* __restrict__ w_ff1, const float* __restrict__ w_ff2,
    const float* __restrict__ gat_w, short* __restrict__ wbf)
{
    __shared__ float s_t[64][65];
    const int tid = threadIdx.x;
    int t = blockIdx.x;
    const float* src; short* dst; int R, C, tr, tc;
    if (t >= 96) { int q = t - 96; src = gat_w; dst = wbf + WOFF_GATW; R = 64; C = 128; tr = 0; tc = q; }
    else {
        int layer = t / 32, r32 = t % 32;
        if (r32 < 12)      { src = tw_qkv + layer * (128*384); dst = wbf + WOFF_QKV(layer); R = 128; C = 384; tr = r32 / 6;  tc = r32 % 6; }
        else if (r32 < 16) { int q = r32 - 12; src = tw_o + layer * 16384; dst = wbf + WOFF_O(layer);  R = 128; C = 128; tr = q >> 1; tc = q & 1; }
        else if (r32 < 24) { int q = r32 - 16; src = w_ff1 + layer * 32768; dst = wbf + WOFF_FF1(layer); R = 128; C = 256; tr = q >> 2; tc = q & 3; }
        else               { int q = r32 - 24; src = w_ff2 + layer * 32768; dst = wbf + WOFF_FF2(layer); R = 256; C = 128; tr = q >> 1; tc = q & 1; }
    }
    #pragma unroll
    for (int it = 0; it < 16; ++it) {
        int e = it * 256 + tid;
        int r = e >> 6, c = e & 63;
        s_t[r][c] = src[(size_t)(tr*64 + r) * C + tc*64 + c];
    }
    __syncthreads();
    #pragma unroll
    for (int it = 0; it < 16; ++it) {
        int e = it * 256 + tid;
        int c = e >> 6, r = e & 63;
        dst[(size_t)(tc*64 + c) * R + tr*64 + r] = (short)bf16_rne(s_t[r][c]);
    }
}

// ---------------------------------------------------------------------------
// MFMA helpers: A stored [rows][K] bf16 LDS, swizzle kelem ^ ((row&7)<<3).
__device__ __forceinline__ bf16x8 ld_frag(const short* s, int row, int kbase, int ldk) {
    return *(const bf16x8*)&s[row * ldk + (kbase ^ ((row & 7) << 3))];
}
// stage 64x128 fp32 -> bf16 swizzled LDS
__device__ __forceinline__ void stage_a(short* s_a, const float* __restrict__ src, int tid) {
    const float2* s2 = (const float2*)src;
    #pragma unroll
    for (int it = 0; it < 16; ++it) {
        int i2 = it * 256 + tid;
        int row = i2 >> 6, ke = (i2 & 63) * 2;
        float2 v = s2[i2];
        *(unsigned*)&s_a[row * 128 + (ke ^ ((row & 7) << 3))] = bf16pk(v.x, v.y);
    }
}
// stage 128 rows x 128 k of contiguous bf16 [N][128] -> swizzled LDS
__device__ __forceinline__ void stage_b(short* s_b, const short* __restrict__ src, int tid) {
    const uint4* s4 = (const uint4*)src;
    #pragma unroll
    for (int it = 0; it < 8; ++it) {
        int c = it * 256 + tid;
        int row = c >> 4, ke = (c & 15) * 8;
        *(uint4*)&s_b[row * 128 + (ke ^ ((row & 7) << 3))] = s4[c];
    }
}

// ---------------------------------------------------------------------------
// G1: x -> GCN(tanh) -> h = gcn @ gat_w (MFMA) -> h (bf16 global), a_s/a_d (global)
__global__ __launch_bounds__(256) void gcn_h_mfma(
    const float* __restrict__ x, const float* __restrict__ gcn_w, const float* __restrict__ gcn_b,
    const float* __restrict__ a_src, const float* __restrict__ a_dst,
    const float* __restrict__ ws, const short* __restrict__ gwT,
    short* __restrict__ hbuf, float* __restrict__ asb, float* __restrict__ adb)
{
    __shared__ float s_x[16 * 50];
    __shared__ float s_an[25];
    __shared__ short s_gcn[80 * 64];     // bf16, swizzled

    const int tid = threadIdx.x;
    const int tok0 = blockIdx.x * 16;

    for (int i = tid; i < 16 * 50; i += 256) s_x[i] = x[(size_t)tok0 * 50 + i];
    if (tid < 25) s_an[tid] = ws[tid];
    __syncthreads();

    #pragma unroll
    for (int it = 0; it < 2; ++it) {
        int idx = it * 256 + tid;
        int tl = idx >> 5, kp = idx & 31;
        int k0 = kp * 2;
        float w0[F_], w1[F_];
        #pragma unroll
        for (int f = 0; f < F_; ++f) { w0[f] = gcn_w[f * 64 + k0]; w1[f] = gcn_w[f * 64 + k0 + 1]; }
        float b0 = gcn_b[k0], b1 = gcn_b[k0 + 1];
        float xw0[N_], xw1[N_];
        #pragma unroll
        for (int n = 0; n < N_; ++n) {
            float a0 = b0, a1 = b1;
            #pragma unroll
            for (int f = 0; f < F_; ++f) {
                float xv = s_x[tl * 50 + n * 10 + f];
                a0 += xv * w0[f]; a1 += xv * w1[f];
            }
            xw0[n] = a0; xw1[n] = a1;
        }
        #pragma unroll
        for (int n = 0; n < N_; ++n) {
            float s0 = 0.f, s1 = 0.f;
            #pragma unroll
            for (int j = 0; j < N_; ++j) { float an = s_an[n * 5 + j]; s0 += an * xw0[j]; s1 += an * xw1[j]; }
            float e0 = __expf(2.f * fabsf(s0)), e1 = __expf(2.f * fabsf(s1));
            float t0 = copysignf(1.f - 2.f / (e0 + 1.f), s0);
            float t1 = copysignf(1.f - 2.f / (e1 + 1.f), s1);
            int row = tl * 5 + n;
            *(unsigned*)&s_gcn[row * 64 + (k0 ^ ((row & 7) << 3))] = bf16pk(t0, t1);
        }
    }
    __syncthreads();

    const int w = tid >> 6, lane = tid & 63;
    const int c = lane & 15, g = lane >> 4;
    const int kf = g * 8;
    bf16x8 bfr[2][2];
    #pragma unroll
    for (int nn = 0; nn < 2; ++nn)
        #pragma unroll
        for (int k0 = 0; k0 < 2; ++k0)
            bfr[nn][k0] = *(const bf16x8*)&gwT[(w * 32 + nn * 16 + c) * 64 + k0 * 32 + kf];
    const float as0 = a_src[w * 32 + c],      as1 = a_src[w * 32 + 16 + c];
    const float ad0 = a_dst[w * 32 + c],      ad1 = a_dst[w * 32 + 16 + c];
    #pragma unroll
    for (int m = 0; m < 5; ++m) {
        bf16x8 af0 = ld_frag(s_gcn, m * 16 + c, kf, 64);
        bf16x8 af1 = ld_frag(s_gcn, m * 16 + c, 32 + kf, 64);
        f32x4 a0 = {0,0,0,0}, a1 = {0,0,0,0};
        a0 = __builtin_amdgcn_mfma_f32_16x16x32_bf16(af0, bfr[0][0], a0, 0, 0, 0);
        a0 = __builtin_amdgcn_mfma_f32_16x16x32_bf16(af1, bfr[0][1], a0, 0, 0, 0);
        a1 = __builtin_amdgcn_mfma_f32_16x16x32_bf16(af0, bfr[1][0], a1, 0, 0, 0);
        a1 = __builtin_amdgcn_mfma_f32_16x16x32_bf16(af1, bfr[1][1], a1, 0, 0, 0);
        float ps[4], pd[4];
        #pragma unroll
        for (int i = 0; i < 4; ++i) {
            int row = m * 16 + g * 4 + i;
            size_t gr = (size_t)(tok0 * 5 + row) * 128;
            hbuf[gr + w * 32 + c]      = (short)bf16_rne(a0[i]);
            hbuf[gr + w * 32 + 16 + c] = (short)bf16_rne(a1[i]);
            ps[i] = a0[i] * as0 + a1[i] * as1;
            pd[i] = a0[i] * ad0 + a1[i] * ad1;
        }
        #pragma unroll
        for (int mm = 1; mm < 16; mm <<= 1)
            #pragma unroll
            for (int i = 0; i < 4; ++i) { ps[i] += __shfl_xor(ps[i], mm); pd[i] += __shfl_xor(pd[i], mm); }
        if (c == 0) {
            #pragma unroll
            for (int i = 0; i < 4; ++i) {
                int row = m * 16 + g * 4 + i;
                asb[(size_t)(tok0 * 5 + row) * 4 + w] = ps[i];
                adb[(size_t)(tok0 * 5 + row) * 4 + w] = pd[i];
            }
        }
    }
}

// ---------------------------------------------------------------------------
// G2: alpha softmax + aggregate + gat_b + LN + mean + PE -> z
__global__ __launch_bounds__(256) void gat_agg(
    const short* __restrict__ hbuf, const float* __restrict__ asb, const float* __restrict__ adb,
    const float* __restrict__ gat_b, const float* __restrict__ gln_g, const float* __restrict__ gln_b,
    const float* __restrict__ ws, float* __restrict__ z, int E2)
{
    __shared__ int   s_src[E2MAX], s_csr_off[N_ + 1], s_csr_e[E2MAX];
    __shared__ float s_alpha[4][E2MAX][4];
    __shared__ short s_h[4 * 5 * 128];

    const int tid = threadIdx.x;
    const int wv = tid >> 6, lane = tid & 63;
    const int tok = blockIdx.x * 4 + wv;
    const int* wsi = (const int*)ws;

    if (tid < E2) { s_src[tid] = wsi[32 + tid]; s_csr_e[tid] = wsi[104 + tid]; }
    if (tid < N_ + 1) s_csr_off[tid] = wsi[96 + tid];
    {
        const uint4* hb4 = (const uint4*)(hbuf + (size_t)blockIdx.x * 4 * 5 * 128);
        uint4* sh4 = (uint4*)s_h;
        #pragma unroll
        for (int it = 0; it < 2; ++it) {
            int i = it * 256 + tid;
            if (i < 320) sh4[i] = hb4[i];
        }
    }
    __syncthreads();

    if (lane < 20) {
        int dn = lane >> 2, head = lane & 3;
        int j0 = s_csr_off[dn], j1 = s_csr_off[dn + 1];
        float adv = adb[(size_t)(tok * 5 + dn) * 4 + head];
        float mx = -1e30f;
        for (int j = j0; j < j1; ++j) {
            int e = s_csr_e[j];
            float ev = asb[(size_t)(tok * 5 + s_src[e]) * 4 + head] + adv;
            ev = ev > 0.f ? ev : 0.2f * ev;
            mx = fmaxf(mx, ev);
        }
        float den = 0.f;
        for (int j = j0; j < j1; ++j) {
            int e = s_csr_e[j];
            float ev = asb[(size_t)(tok * 5 + s_src[e]) * 4 + head] + adv;
            ev = ev > 0.f ? ev : 0.2f * ev;
            float ex = __expf(ev - mx);
            den += ex;
            s_alpha[wv][e][head] = ex;
        }
        float r = 1.f / den;
        for (int j = j0; j < j1; ++j) s_alpha[wv][s_csr_e[j]][head] *= r;
    }
    __syncthreads();

    const int h0 = lane >> 5, h1 = 2 + (lane >> 5);
    const float gb0 = gat_b[lane],      gb1 = gat_b[lane + 64];
    const float gg0 = gln_g[lane],      gg1 = gln_g[lane + 64];
    const float gB0 = gln_b[lane],      gB1 = gln_b[lane + 64];
    float v0[N_], v1[N_];
    #pragma unroll
    for (int n = 0; n < N_; ++n) {
        float a0 = 0.f, a1 = 0.f;
        int j0 = s_csr_off[n], j1 = s_csr_off[n + 1];
        for (int j = j0; j < j1; ++j) {
            int e = s_csr_e[j];
            int rb = (wv * 5 + s_src[e]) * 128;
            a0 += s_alpha[wv][e][h0] * bf2f(s_h[rb + lane]);
            a1 += s_alpha[wv][e][h1] * bf2f(s_h[rb + lane + 64]);
        }
        v0[n] = a0 + gb0; v1[n] = a1 + gb1;
    }
    float r1[N_], r2[N_];
    #pragma unroll
    for (int n = 0; n < N_; ++n) { r1[n] = v0[n] + v1[n]; r2[n] = v0[n]*v0[n] + v1[n]*v1[n]; }
    #pragma unroll
    for (int mm = 1; mm < 64; mm <<= 1)
        #pragma unroll
        for (int n = 0; n < N_; ++n) { r1[n] += __shfl_xor(r1[n], mm); r2[n] += __shfl_xor(r2[n], mm); }
    float z0 = 0.f, z1 = 0.f;
    #pragma unroll
    for (int n = 0; n < N_; ++n) {
        float mu = r1[n] * (1.f / D_);
        float var = r2[n] * (1.f / D_) - mu * mu;
        float rstd = rsqrtf(var + 1e-5f);
        z0 += (v0[n] - mu) * rstd * gg0 + gB0;
        z1 += (v1[n] - mu) * rstd * gg1 + gB1;
    }
    z0 *= (1.f / N_); z1 *= (1.f / N_);
    const float cpe = -9.210340371976184f / (float)D_;
    int t = tok % T_;
    float dv0 = __expf((float)(lane & ~1) * cpe);
    float dv1 = __expf((float)((lane + 64) & ~1) * cpe);
    float ang0 = (float)t * dv0, ang1 = (float)t * dv1;
    z0 += (lane & 1) ? __cosf(ang0) : __sinf(ang0);
    z1 += (lane & 1) ? __cosf(ang1) : __sinf(ang1);
    z[(size_t)tok * D_ + lane] = z0;
    z[(size_t)tok * D_ + 64 + lane] = z1;
}

// ---------------------------------------------------------------------------
// qkv = z @ Wqkv + b : M-tile 64, 4 waves, 3 N-chunks of 128
__global__ __launch_bounds__(256) void qkv_mfma(
    const float* __restrict__ z, const short* __restrict__ WT, const float* __restrict__ bias,
    float* __restrict__ qkv)
{
    __shared__ short s_a[64 * 128];
    __shared__ short s_b[128 * 128];
    const int tid = threadIdx.x;
    const int w = tid >> 6, lane = tid & 63;
    const int tok0 = blockIdx.x * 64;
    stage_a(s_a, z + (size_t)tok0 * 128, tid);
    __syncthreads();
    bf16x8 af[4];
    const int arow = w * 16 + (lane & 15);
    const int kf = (lane >> 4) * 8;
    #pragma unroll
    for (int k0 = 0; k0 < 4; ++k0) af[k0] = ld_frag(s_a, arow, k0 * 32 + kf, 128);

    for (int ch = 0; ch < 3; ++ch) {
        __syncthreads();
        stage_b(s_b, WT + ch * 128 * 128, tid);
        __syncthreads();
        #pragma unroll
        for (int n0 = 0; n0 < 8; ++n0) {
            const int ncol = ch * 128 + n0 * 16 + (lane & 15);
            const int brow = n0 * 16 + (lane & 15);
            float bv = bias[ncol];
            f32x4 acc = {bv, bv, bv, bv};
            #pragma unroll
            for (int k0 = 0; k0 < 4; ++k0) {
                bf16x8 bfg = ld_frag(s_b, brow, k0 * 32 + kf, 128);
                acc = __builtin_amdgcn_mfma_f32_16x16x32_bf16(af[k0], bfg, acc, 0, 0, 0);
            }
            const int r0 = tok0 + w * 16 + (lane >> 4) * 4;
            #pragma unroll
            for (int i = 0; i < 4; ++i)
                qkv[(size_t)(r0 + i) * 384 + ncol] = acc[i];
        }
    }
}

// ---------------------------------------------------------------------------
// MFMA attention for one (batch, head). 4 waves; waves round-robin the 5 M-tiles.
// Q,K bf16 [80][40] (pad rows zeroed); V^T bf16 [32][104]; P bf16 [80][104].
// Single barrier: each wave's PV reads only P rows it wrote itself.
__global__ __launch_bounds__(256) void attn_mfma(
    const float* __restrict__ qkv, float* __restrict__ obuf)
{
    __shared__ short s_q[80 * 40];
    __shared__ short s_k[80 * 40];
    __shared__ short s_vt[32 * 104];
    __shared__ short s_p[80 * 104];

    const int bh = blockIdx.x;
    const int b = bh >> 2, h = bh & 3;
    const int tid = threadIdx.x;
    const int w = tid >> 6, lane = tid & 63;
    const int c = lane & 15, g = lane >> 4;
    const float* base = qkv + (size_t)b * T_ * 384 + h * 32;

    // ---- stage Q, K (pad rows 72..79 = 0)
    for (int idx = tid; idx < 80 * 32; idx += 256) {
        int row = idx >> 5, cc = idx & 31;
        float qv = 0.f, kv = 0.f;
        if (row < T_) {
            qv = base[row * 384 + cc];
            kv = base[row * 384 + 128 + cc];
        }
        s_q[row * 40 + cc] = (short)bf16_rne(qv);
        s_k[row * 40 + cc] = (short)bf16_rne(kv);
    }
    // ---- stage V^T (keys 72..95 = 0)
    for (int idx = tid; idx < 80 * 32; idx += 256) {
        int key = idx >> 5, cc = idx & 31;
        float vv = (key < T_) ? base[key * 384 + 256 + cc] : 0.f;
        s_vt[cc * 104 + key] = (short)bf16_rne(vv);
    }
    for (int idx = tid; idx < 32 * 24; idx += 256) {
        int cc = idx / 24, key = 80 + idx % 24;  // zero VT keys 80..103 (72..79 done above)
        s_vt[cc * 104 + key] = 0;
    }
    // ---- zero P pad cols 80..103
    for (int idx = tid; idx < 80 * 24; idx += 256) {
        int row = idx / 24, col = 80 + idx % 24;
        s_p[row * 104 + col] = 0;
    }
    __syncthreads();

    const float scale = 0.17677669529663687f; // 1/sqrt(32)

    for (int m = w; m < 5; m += 4) {
        // ---- S tile row m: 5 mfma over N-tiles
        bf16x8 aq = *(const bf16x8*)&s_q[(m * 16 + c) * 40 + g * 8];
        f32x4 accS[5];
        #pragma unroll
        for (int n0 = 0; n0 < 5; ++n0) {
            bf16x8 bk = *(const bf16x8*)&s_k[(n0 * 16 + c) * 40 + g * 8];
            f32x4 z4 = {0,0,0,0};
            accS[n0] = __builtin_amdgcn_mfma_f32_16x16x32_bf16(aq, bk, z4, 0, 0, 0);
        }
        // ---- softmax across the 80 cols (mask cols >= 72), in-register
        float ps[5][4];
        float mx[4], den[4];
        #pragma unroll
        for (int i = 0; i < 4; ++i) mx[i] = -1e30f;
        #pragma unroll
        for (int n0 = 0; n0 < 5; ++n0)
            #pragma unroll
            for (int i = 0; i < 4; ++i) {
                float s = accS[n0][i] * scale;
                if (n0 == 4 && c >= 8) s = -1e30f;
                ps[n0][i] = s;
                mx[i] = fmaxf(mx[i], s);
            }
        #pragma unroll
        for (int mm = 1; mm < 16; mm <<= 1)
            #pragma unroll
            for (int i = 0; i < 4; ++i) mx[i] = fmaxf(mx[i], __shfl_xor(mx[i], mm));
        #pragma unroll
        for (int i = 0; i < 4; ++i) den[i] = 0.f;
        #pragma unroll
        for (int n0 = 0; n0 < 5; ++n0)
            #pragma unroll
            for (int i = 0; i < 4; ++i) {
                float e = __expf(ps[n0][i] - mx[i]);
                ps[n0][i] = e;
                den[i] += e;
            }
        #pragma unroll
        for (int mm = 1; mm < 16; mm <<= 1)
            #pragma unroll
            for (int i = 0; i < 4; ++i) den[i] += __shfl_xor(den[i], mm);
        float rden[4];
        #pragma unroll
        for (int i = 0; i < 4; ++i) rden[i] = 1.f / den[i];
        // ---- write P rows (bf16) to LDS
        #pragma unroll
        for (int n0 = 0; n0 < 5; ++n0)
            #pragma unroll
            for (int i = 0; i < 4; ++i) {
                int row = m * 16 + g * 4 + i;
                s_p[row * 104 + n0 * 16 + c] = (short)bf16_rne(ps[n0][i] * rden[i]);
            }
        // ---- PV: O rows of tile m (reads only this wave's P rows)
        f32x4 accO[2] = {{0,0,0,0},{0,0,0,0}};
        #pragma unroll
        for (int kt = 0; kt < 3; ++kt) {
            bf16x8 ap = *(const bf16x8*)&s_p[(m * 16 + c) * 104 + kt * 32 + g * 8];
            #pragma unroll
            for (int n0 = 0; n0 < 2; ++n0) {
                bf16x8 bv = *(const bf16x8*)&s_vt[(n0 * 16 + c) * 104 + kt * 32 + g * 8];
                accO[n0] = __builtin_amdgcn_mfma_f32_16x16x32_bf16(ap, bv, accO[n0], 0, 0, 0);
            }
        }
        #pragma unroll
        for (int n0 = 0; n0 < 2; ++n0)
            #pragma unroll
            for (int i = 0; i < 4; ++i) {
                int row = m * 16 + g * 4 + i;
                if (row < T_)
                    obuf[(size_t)(b * T_ + row) * D_ + h * 32 + n0 * 16 + c] = accO[n0][i];
            }
    }
}

// ---------------------------------------------------------------------------
// Fused: z1 = LN1(z + obuf@Wo + bo); z = LN2(z1 + relu(z1@W1+b1)@W2 + b2)
__global__ __launch_bounds__(256) void oproj_ff_mfma(
    const float* __restrict__ obuf, const short* __restrict__ WoT, const float* __restrict__ bo,
    const float* __restrict__ g1, const float* __restrict__ be1,
    const short* __restrict__ W1T, const float* __restrict__ b1,
    const short* __restrict__ W2T, const float* __restrict__ b2,
    const float* __restrict__ g2, const float* __restrict__ be2,
    float* __restrict__ z)
{
    __shared__ short s_a[64 * 128];
    __shared__ short s_b[128 * 128];
    __shared__ short s_f[64 * 256];
    const int tid = threadIdx.x;
    const int w = tid >> 6, lane = tid & 63;
    const int tok0 = blockIdx.x * 64;
    const int cbase = lane & 15;
    const int arow = w * 16 + cbase;
    const int kf = (lane >> 4) * 8;
    const int r0 = tok0 + w * 16 + (lane >> 4) * 4;
    const int lrow0 = w * 16 + (lane >> 4) * 4;

    stage_a(s_a, obuf + (size_t)tok0 * 128, tid);
    stage_b(s_b, WoT, tid);
    __syncthreads();
    bf16x8 af[4];
    #pragma unroll
    for (int k0 = 0; k0 < 4; ++k0) af[k0] = ld_frag(s_a, arow, k0 * 32 + kf, 128);

    f32x4 acc[8];
    #pragma unroll
    for (int n0 = 0; n0 < 8; ++n0) {
        float bv = bo[n0 * 16 + cbase];
        acc[n0] = (f32x4){bv, bv, bv, bv};
        const int brow = n0 * 16 + cbase;
        #pragma unroll
        for (int k0 = 0; k0 < 4; ++k0) {
            bf16x8 bfg = ld_frag(s_b, brow, k0 * 32 + kf, 128);
            acc[n0] = __builtin_amdgcn_mfma_f32_16x16x32_bf16(af[k0], bfg, acc[n0], 0, 0, 0);
        }
    }
    #pragma unroll
    for (int n0 = 0; n0 < 8; ++n0)
        #pragma unroll
        for (int i = 0; i < 4; ++i)
            acc[n0][i] += z[(size_t)(r0 + i) * 128 + n0 * 16 + cbase];
    {
        float s1[4] = {0,0,0,0}, s2[4] = {0,0,0,0};
        #pragma unroll
        for (int n0 = 0; n0 < 8; ++n0)
            #pragma unroll
            for (int i = 0; i < 4; ++i) { float v = acc[n0][i]; s1[i] += v; s2[i] += v * v; }
        #pragma unroll
        for (int m = 1; m < 16; m <<= 1)
            #pragma unroll
            for (int i = 0; i < 4; ++i) { s1[i] += __shfl_xor(s1[i], m); s2[i] += __shfl_xor(s2[i], m); }
        #pragma unroll
        for (int i = 0; i < 4; ++i) {
            float mu = s1[i] * (1.f / D_);
            float var = s2[i] * (1.f / D_) - mu * mu;
            float rstd = rsqrtf(var + 1e-5f);
            #pragma unroll
            for (int n0 = 0; n0 < 8; ++n0) {
                float gv = g1[n0 * 16 + cbase], bev = be1[n0 * 16 + cbase];
                acc[n0][i] = (acc[n0][i] - mu) * rstd * gv + bev;
            }
        }
    }
    #pragma unroll
    for (int n0 = 0; n0 < 8; ++n0)
        #pragma unroll
        for (int i = 0; i < 4; ++i) {
            int row = lrow0 + i;
            s_a[row * 128 + ((n0 * 16 + cbase) ^ ((row & 7) << 3))] = (short)bf16_rne(acc[n0][i]);
        }
    bf16x8 af1[4];
    #pragma unroll
    for (int k0 = 0; k0 < 4; ++k0) af1[k0] = ld_frag(s_a, arow, k0 * 32 + kf, 128);

    for (int ch = 0; ch < 2; ++ch) {
        __syncthreads();
        stage_b(s_b, W1T + ch * 128 * 128, tid);
        __syncthreads();
        #pragma unroll
        for (int n0 = 0; n0 < 8; ++n0) {
            const int ncol = ch * 128 + n0 * 16 + cbase;
            const int brow = n0 * 16 + cbase;
            float bv = b1[ncol];
            f32x4 a = {bv, bv, bv, bv};
            #pragma unroll
            for (int k0 = 0; k0 < 4; ++k0) {
                bf16x8 bfg = ld_frag(s_b, brow, k0 * 32 + kf, 128);
                a = __builtin_amdgcn_mfma_f32_16x16x32_bf16(af1[k0], bfg, a, 0, 0, 0);
            }
            #pragma unroll
            for (int i = 0; i < 4; ++i) {
                int row = lrow0 + i;
                s_f[row * 256 + (ncol ^ ((row & 7) << 3))] = (short)bf16_rne(fmaxf(a[i], 0.f));
            }
        }
    }
    f32x4 acc2[8];
    #pragma unroll
    for (int n0 = 0; n0 < 8; ++n0) {
        float bv = b2[n0 * 16 + cbase];
        acc2[n0] = (f32x4){bv, bv, bv, bv};
    }
    for (int kc = 0; kc < 2; ++kc) {
        __syncthreads();
        #pragma unroll
        for (int it = 0; it < 8; ++it) {
            int cc = it * 256 + tid;
            int row = cc >> 4, ke = (cc & 15) * 8;
            uint4 v = *(const uint4*)&W2T[row * 256 + kc * 128 + ke];
            *(uint4*)&s_b[row * 128 + (ke ^ ((row & 7) << 3))] = v;
        }
        __syncthreads();
        bf16x8 af2[4];
        #pragma unroll
        for (int k0 = 0; k0 < 4; ++k0)
            af2[k0] = ld_frag(s_f, arow, kc * 128 + k0 * 32 + kf, 256);
        #pragma unroll
        for (int n0 = 0; n0 < 8; ++n0) {
            const int brow = n0 * 16 + cbase;
            #pragma unroll
            for (int k0 = 0; k0 < 4; ++k0) {
                bf16x8 bfg = ld_frag(s_b, brow, k0 * 32 + kf, 128);
                acc2[n0] = __builtin_amdgcn_mfma_f32_16x16x32_bf16(af2[k0], bfg, acc2[n0], 0, 0, 0);
            }
        }
    }
    #pragma unroll
    for (int n0 = 0; n0 < 8; ++n0)
        #pragma unroll
        for (int i = 0; i < 4; ++i)
            acc2[n0][i] += acc[n0][i];
    float s1[4] = {0,0,0,0}, s2[4] = {0,0,0,0};
    #pragma unroll
    for (int n0 = 0; n0 < 8; ++n0)
        #pragma unroll
        for (int i = 0; i < 4; ++i) { float v = acc2[n0][i]; s1[i] += v; s2[i] += v * v; }
    #pragma unroll
    for (int m = 1; m < 16; m <<= 1)
        #pragma unroll
        for (int i = 0; i < 4; ++i) { s1[i] += __shfl_xor(s1[i], m); s2[i] += __shfl_xor(s2[i], m); }
    #pragma unroll
    for (int i = 0; i < 4; ++i) {
        float mu = s1[i] * (1.f / D_);
        float var = s2[i] * (1.f / D_) - mu * mu;
        float rstd = rsqrtf(var + 1e-5f);
        #pragma unroll
        for (int n0 = 0; n0 < 8; ++n0) {
            float gv = g2[n0 * 16 + cbase], bev = be2[n0 * 16 + cbase];
            z[(size_t)(r0 + i) * 128 + n0 * 16 + cbase] = (acc2[n0][i] - mu) * rstd * gv + bev;
        }
    }
}

// ---------------------------------------------------------------------------
__global__ __launch_bounds__(64) void heads_kernel(
    const float* __restrict__ z, const float* __restrict__ hw1, const float* __restrict__ hb1,
    const float* __restrict__ hw2, const float* __restrict__ hb2, float* __restrict__ out)
{
    const int k = blockIdx.x >> 8;
    const int b = blockIdx.x & 255;
    const int tid = threadIdx.x;
    __shared__ float s_last[D_];
    __shared__ float s_h1[64];
    const float* zr = z + (size_t)(b * T_ + (T_ - 1)) * D_;
    s_last[tid] = zr[tid];
    s_last[tid + 64] = zr[tid + 64];
    __syncthreads();
    float acc = hb1[k * 64 + tid];
    const float* w1 = hw1 + (size_t)k * D_ * 64;
    for (int dd = 0; dd < D_; ++dd) acc += s_last[dd] * w1[dd * 64 + tid];
    s_h1[tid] = fmaxf(acc, 0.f);
    __syncthreads();
    if (tid < 5) {
        float o = hb2[k * 5 + tid];
        const float* w2 = hw2 + (size_t)k * 64 * 5;
        for (int j = 0; j < 64; ++j) o += s_h1[j] * w2[j * 5 + tid];
        out[(size_t)k * (B_ * 5) + b * 5 + tid] = o;
    }
}

// ---------------------------------------------------------------------------
extern "C" void kernel_launch(void* const* d_in, const int* in_sizes, int n_in,
                              void* d_out, int out_size, void* d_ws, size_t ws_size,
                              hipStream_t stream) {
    const float* x      = (const float*)d_in[0];
    const int*   ei     = (const int*)  d_in[1];
    const float* gcn_w  = (const float*)d_in[2];
    const float* gcn_b  = (const float*)d_in[3];
    const float* gat_w  = (const float*)d_in[4];
    const float* a_src  = (const float*)d_in[5];
    const float* a_dst  = (const float*)d_in[6];
    const float* gat_b  = (const float*)d_in[7];
    const float* gln_g  = (const float*)d_in[8];
    const float* gln_b  = (const float*)d_in[9];
    const float* tw_qkv = (const float*)d_in[10];
    const float* tb_qkv = (const float*)d_in[11];
    const float* tw_o   = (const float*)d_in[12];
    const float* tb_o   = (const float*)d_in[13];
    const float* ln1_g  = (const float*)d_in[14];
    const float* ln1_b  = (const float*)d_in[15];
    const float* w_ff1  = (const float*)d_in[16];
    const float* b_ff1  = (const float*)d_in[17];
    const float* w_ff2  = (const float*)d_in[18];
    const float* b_ff2  = (const float*)d_in[19];
    const float* ln2_g  = (const float*)d_in[20];
    const float* ln2_b  = (const float*)d_in[21];
    const float* hw1    = (const float*)d_in[22];
    const float* hb1    = (const float*)d_in[23];
    const float* hw2    = (const float*)d_in[24];
    const float* hb2    = (const float*)d_in[25];
    float* out = (float*)d_out;
    float* ws  = (float*)d_ws;

    float* z    = ws + WS_Z;
    float* qkv  = ws + WS_QKV;
    float* obuf = ws + WS_OBUF;
    short* wbf  = (short*)(ws + WS_WBF);

    short* hbuf = (short*)(ws + WS_QKV);       // graph scratch aliases qkv
    float* asb  = ws + WS_OBUF;
    float* adb  = ws + WS_OBUF + BT_ * 5 * 4;

    const int E = in_sizes[1] / 2;   // 20
    const int E2 = E + N_;           // 25

    setup_kernel<<<1, 64, 0, stream>>>(ei, ws, E);
    prep_kernel<<<98, 256, 0, stream>>>(tw_qkv, tw_o, w_ff1, w_ff2, gat_w, wbf);
    gcn_h_mfma<<<BT_ / 16, 256, 0, stream>>>(x, gcn_w, gcn_b, a_src, a_dst, ws,
                                             wbf + WOFF_GATW, hbuf, asb, adb);
    gat_agg<<<BT_ / 4, 256, 0, stream>>>(hbuf, asb, adb, gat_b, gln_g, gln_b, ws, z, E2);
    for (int i = 0; i < 3; ++i) {
        qkv_mfma<<<BT_ / 64, 256, 0, stream>>>(z, wbf + WOFF_QKV(i),
                                               tb_qkv + (size_t)i * 3 * D_, qkv);
        attn_mfma<<<B_ * HH_, 256, 0, stream>>>(qkv, obuf);
        oproj_ff_mfma<<<BT_ / 64, 256, 0, stream>>>(obuf, wbf + WOFF_O(i),
                                                    tb_o + (size_t)i * D_,
                                                    ln1_g + (size_t)i * D_, ln1_b + (size_t)i * D_,
                                                    wbf + WOFF_FF1(i), b_ff1 + (size_t)i * FF_,
                                                    wbf + WOFF_FF2(i), b_ff2 + (size_t)i * D_,
                                                    ln2_g + (size_t)i * D_, ln2_b + (size_t)i * D_, z);
    }
    heads_kernel<<<6 * B_, 64, 0, stream>>>(z, hw1, hb1, hw2, hb2, out);
}